// Round 7
// baseline (365.023 us; speedup 1.0000x reference)
//
#include <hip/hip_runtime.h>
#include <hip/hip_cooperative_groups.h>

namespace cg = cooperative_groups;

// ---------------------------------------------------------------------------
// PromptSelector — collapsed-algebra + single cooperative kernel.
// scores[b,h,j] = rden_j*(dot(ga*x_j, wk[:,h]) - mean_j*Sgw[h]) + CgbC[h]
// u[b,h,:]      = ga ⊙ (Σ_j q_j x_j − c1) + gb,  q_j = p_j·rden_j, c1 = Σ q_j·mean_j
// 3 launches: prep_a (q0 + colga/colgb), prep_b (wkq + consts), fused_k
// (scores→softmax→upart→o0→x2→f1→x3→logits→decide→gather, 9 grid.sync()).
// ---------------------------------------------------------------------------

#define OUT_CLS_OFF 614400   // 8*100*768

__device__ __forceinline__ float bsum256(float v, float* red) {
    int lane = threadIdx.x & 63, w = threadIdx.x >> 6;
#pragma unroll
    for (int off = 1; off < 64; off <<= 1) v += __shfl_xor(v, off);
    __syncthreads();
    if (lane == 0) red[w] = v;
    __syncthreads();
    return red[0] + red[1] + red[2] + red[3];
}
__device__ __forceinline__ float bmax256(float v, float* red) {
    int lane = threadIdx.x & 63, w = threadIdx.x >> 6;
#pragma unroll
    for (int off = 1; off < 64; off <<= 1) v = fmaxf(v, __shfl_xor(v, off));
    __syncthreads();
    if (lane == 0) red[w] = v;
    __syncthreads();
    return fmaxf(fmaxf(red[0], red[1]), fmaxf(red[2], red[3]));
}

// ---------------------------------------------------------------------------
// prep_a: blocks 0-11 -> q0 = LN1(cls) @ Wq + bq (64 cols each).
//         blocks 12-23 -> colga/colgb: ga/gb-weighted column sums of Wk.
__global__ __launch_bounds__(256) void prep_a(
    const float* __restrict__ clsT, const float* __restrict__ ga,
    const float* __restrict__ gb, const float* __restrict__ Wq,
    const float* __restrict__ bq, const float* __restrict__ Wk,
    float* __restrict__ q0, float* __restrict__ colw)
{
    __shared__ float ys[768];
    __shared__ float red[4];
    __shared__ float4 partA[16][17];
    __shared__ float4 partB[16][17];
    int t = threadIdx.x;
    if (blockIdx.x < 12) {
        float a0 = clsT[t], a1 = clsT[t + 256], a2 = clsT[t + 512];
        float mean = bsum256(a0 + a1 + a2, red) * (1.0f / 768.0f);
        float d0 = a0 - mean, d1 = a1 - mean, d2 = a2 - mean;
        float var = bsum256(d0 * d0 + d1 * d1 + d2 * d2, red) * (1.0f / 767.0f);
        float den = sqrtf(var) + 1e-6f;
        ys[t]       = (ga[t] * d0) / den + gb[t];
        ys[t + 256] = (ga[t + 256] * d1) / den + gb[t + 256];
        ys[t + 512] = (ga[t + 512] * d2) / den + gb[t + 512];
        __syncthreads();
        int c = blockIdx.x * 64 + (t & 15) * 4;
        int kq = t >> 4;
        float4 acc = {0.f, 0.f, 0.f, 0.f};
#pragma unroll 8
        for (int i = 0; i < 48; ++i) {
            int k = kq * 48 + i;
            float4 w = *(const float4*)&Wq[(size_t)k * 768 + c];
            float y = ys[k];
            acc.x = fmaf(y, w.x, acc.x); acc.y = fmaf(y, w.y, acc.y);
            acc.z = fmaf(y, w.z, acc.z); acc.w = fmaf(y, w.w, acc.w);
        }
        partA[kq][t & 15] = acc;
        __syncthreads();
        if (t < 16) {
            float4 s = {0.f, 0.f, 0.f, 0.f};
#pragma unroll
            for (int i = 0; i < 16; ++i) {
                float4 v = partA[i][t];
                s.x += v.x; s.y += v.y; s.z += v.z; s.w += v.w;
            }
            int cc = blockIdx.x * 64 + t * 4;
            float4 b4 = *(const float4*)&bq[cc];
            q0[cc] = s.x + b4.x; q0[cc + 1] = s.y + b4.y;
            q0[cc + 2] = s.z + b4.z; q0[cc + 3] = s.w + b4.w;
        }
    } else {
        int c = (blockIdx.x - 12) * 64 + (t & 15) * 4;
        int kq = t >> 4;
        float4 aa = {0.f, 0.f, 0.f, 0.f}, ab = {0.f, 0.f, 0.f, 0.f};
#pragma unroll 8
        for (int i = 0; i < 48; ++i) {
            int k = kq * 48 + i;
            float4 w = *(const float4*)&Wk[(size_t)k * 768 + c];
            float g = ga[k], h = gb[k];
            aa.x = fmaf(g, w.x, aa.x); aa.y = fmaf(g, w.y, aa.y);
            aa.z = fmaf(g, w.z, aa.z); aa.w = fmaf(g, w.w, aa.w);
            ab.x = fmaf(h, w.x, ab.x); ab.y = fmaf(h, w.y, ab.y);
            ab.z = fmaf(h, w.z, ab.z); ab.w = fmaf(h, w.w, ab.w);
        }
        partA[kq][t & 15] = aa;
        partB[kq][t & 15] = ab;
        __syncthreads();
        if (t < 16) {
            float4 sa = {0.f, 0.f, 0.f, 0.f}, sb = {0.f, 0.f, 0.f, 0.f};
#pragma unroll
            for (int i = 0; i < 16; ++i) {
                float4 va = partA[i][t], vb = partB[i][t];
                sa.x += va.x; sa.y += va.y; sa.z += va.z; sa.w += va.w;
                sb.x += vb.x; sb.y += vb.y; sb.z += vb.z; sb.w += vb.w;
            }
            int cc = (blockIdx.x - 12) * 64 + t * 4;
            *(float4*)&colw[cc] = sa;
            *(float4*)&colw[768 + cc] = sb;
        }
    }
}

// ---------------------------------------------------------------------------
// prep_b: wkq[k][h] = (Wk[k,h48..] . q0_h)/sqrt(48); block 0 also computes
// Sgw[h] = invs*dot(q0_h, colga_h), CgbC[h] = invs*(dot(q0_h,colgb_h)+bk-dot).
__global__ __launch_bounds__(256) void prep_b(
    const float* __restrict__ Wk, const float* __restrict__ bk,
    const float* __restrict__ q0, const float* __restrict__ colw,
    float* __restrict__ wkqc)
{
    __shared__ float qs[768];
    int t = threadIdx.x;
    qs[t] = q0[t]; qs[t + 256] = q0[t + 256]; qs[t + 512] = q0[t + 512];
    __syncthreads();
    const float invs = 0.14433756729740643f;  // 1/sqrt(48)
    int kl = t >> 4, h = t & 15;
    int k = blockIdx.x * 16 + kl;
    const float* wr = Wk + (size_t)k * 768 + h * 48;
    const float* qh = qs + h * 48;
    float a = 0.f;
#pragma unroll
    for (int d = 0; d < 48; d += 4) {
        float4 w = *(const float4*)&wr[d];
        a += w.x * qh[d] + w.y * qh[d + 1] + w.z * qh[d + 2] + w.w * qh[d + 3];
    }
    wkqc[k * 16 + h] = a * invs;
    if (blockIdx.x == 0 && t < 16) {
        float cd = 0.f, sa = 0.f, sb = 0.f;
        for (int d = 0; d < 48; ++d) {
            int dd = t * 48 + d;
            cd = fmaf(bk[dd], qs[dd], cd);
            sa = fmaf(colw[dd], qs[dd], sa);
            sb = fmaf(colw[768 + dd], qs[dd], sb);
        }
        wkqc[12304 + t] = sa * invs;
        wkqc[12320 + t] = sb * invs + cd * invs;
    }
}

// ---------------------------------------------------------------------------
// fused cooperative kernel: grid 256 x 256 threads, 9 grid syncs.
__global__ __launch_bounds__(256) void fused_k(
    const float* __restrict__ tf, const float* __restrict__ clsT,
    const float* __restrict__ ln1a, const float* __restrict__ ln1b,
    const float* __restrict__ wkqc, float* __restrict__ sc,
    float2* __restrict__ stats, float* __restrict__ qb,
    float* __restrict__ c1w, float* __restrict__ up,
    const float* __restrict__ Wv, const float* __restrict__ bv,
    float* __restrict__ o0, const float* __restrict__ Wo,
    const float* __restrict__ bo, float* __restrict__ x2w,
    const float* __restrict__ ln2a, const float* __restrict__ ln2b,
    const float* __restrict__ W1, const float* __restrict__ b1,
    float* __restrict__ f1w, const float* __restrict__ W2,
    const float* __restrict__ b2, float* __restrict__ x3w,
    const float* __restrict__ lnfa, const float* __restrict__ lnfb,
    const float* __restrict__ Wpool, const float* __restrict__ Wcls,
    double* __restrict__ lp, const float* __restrict__ bpool,
    const float* __restrict__ bcls, const float* __restrict__ pool,
    float* __restrict__ out, int* __restrict__ topw, int* __restrict__ kkw)
{
    cg::grid_group grid = cg::this_grid();
    __shared__ float tr[256][17];
    __shared__ float partw[4][16];
    __shared__ float redw[2][4][2];
    __shared__ float red[4];
    __shared__ float qs_s[16][32];
    __shared__ float us[768];
    __shared__ float part64[4][64];
    __shared__ float ys[3072];
    __shared__ float4 part16[16][17];
    __shared__ float4 part8[8][33];
    __shared__ double sPd[100];
    __shared__ double sC7d[7];

    const int bid = blockIdx.x, t = threadIdx.x;
    const int l = t & 63, w = t >> 6;

    // ============ S1: scores (all 256 blocks, 32 rows each) ============
    {
        float wk0[16], wk1[16], wk2[16];
        const float4* p0 = (const float4*)(wkqc + t * 16);
        const float4* p1 = (const float4*)(wkqc + (t + 256) * 16);
        const float4* p2 = (const float4*)(wkqc + (t + 512) * 16);
#pragma unroll
        for (int q = 0; q < 4; ++q) {
            float4 v0 = p0[q], v1 = p1[q], v2 = p2[q];
            wk0[q * 4] = v0.x; wk0[q * 4 + 1] = v0.y; wk0[q * 4 + 2] = v0.z; wk0[q * 4 + 3] = v0.w;
            wk1[q * 4] = v1.x; wk1[q * 4 + 1] = v1.y; wk1[q * 4 + 2] = v1.z; wk1[q * 4 + 3] = v1.w;
            wk2[q * 4] = v2.x; wk2[q * 4 + 1] = v2.y; wk2[q * 4 + 2] = v2.z; wk2[q * 4 + 3] = v2.w;
        }
        float ga0 = ln1a[t], ga1 = ln1a[t + 256], ga2 = ln1a[t + 512];
        float Sgv = wkqc[12304 + (t & 15)];
        float Cgv = wkqc[12320 + (t & 15)];
        int b = bid >> 5;
        int j0 = (bid & 31) * 32;
        const float* sp0 = j0 ? (tf + ((size_t)b * 1023 + (j0 - 1)) * 768) : clsT;
        float nx0 = sp0[t], nx1 = sp0[t + 256], nx2 = sp0[t + 512];
        for (int r = 0; r < 32; ++r) {
            int j = j0 + r;
            float x0 = nx0, x1 = nx1, x2 = nx2;
            if (r < 31) {   // prefetch next row (tf offset j since next j' = j+1)
                const float* sp = tf + ((size_t)b * 1023 + j) * 768;
                nx0 = sp[t]; nx1 = sp[t + 256]; nx2 = sp[t + 512];
            }
            float s1 = x0 + x1 + x2;
            float s2 = fmaf(x0, x0, fmaf(x1, x1, x2 * x2));
            float g0 = ga0 * x0, g1 = ga1 * x1, g2 = ga2 * x2;
            float dt[16];
#pragma unroll
            for (int h = 0; h < 16; ++h)
                dt[h] = fmaf(g0, wk0[h], fmaf(g1, wk1[h], g2 * wk2[h]));
#pragma unroll
            for (int off = 1; off < 64; off <<= 1) {
                s1 += __shfl_xor(s1, off);
                s2 += __shfl_xor(s2, off);
            }
            if (l == 0) { redw[r & 1][w][0] = s1; redw[r & 1][w][1] = s2; }
#pragma unroll
            for (int h = 0; h < 16; ++h) tr[t][h] = dt[h];
            __syncthreads();
            int hh = t & 15, ch = t >> 4;
            float v = 0.f;
#pragma unroll
            for (int i = 0; i < 16; ++i) v += tr[ch * 16 + i][hh];
            v += __shfl_xor(v, 16);
            v += __shfl_xor(v, 32);
            if (l < 16) partw[w][l] = v;
            __syncthreads();
            if (t < 16) {
                float dtot = partw[0][t] + partw[1][t] + partw[2][t] + partw[3][t];
                float s1t = redw[r & 1][0][0] + redw[r & 1][1][0] + redw[r & 1][2][0] + redw[r & 1][3][0];
                float s2t = redw[r & 1][0][1] + redw[r & 1][1][1] + redw[r & 1][2][1] + redw[r & 1][3][1];
                float mean = s1t * (1.0f / 768.0f);
                float var = (s2t - mean * s1t) * (1.0f / 767.0f);
                float rden = 1.0f / (sqrtf(var) + 1e-6f);
                sc[(((size_t)b * 16 + t) << 10) + j] = rden * (dtot - mean * Sgv) + Cgv;
                if (t == 0) stats[(b << 10) + j] = make_float2(mean, rden);
            }
        }
    }
    grid.sync();

    // ============ S2: softmax + q = p*rden + c1 (blocks < 128) ============
    if (bid < 128) {
        int b = bid >> 4;
        const float4* s4 = (const float4*)(sc + ((size_t)bid << 10));
        float4 v = s4[t];
        float m = fmaxf(fmaxf(v.x, v.y), fmaxf(v.z, v.w));
        float M = bmax256(m, red);
        float e0 = expf(v.x - M), e1 = expf(v.y - M), e2 = expf(v.z - M), e3 = expf(v.w - M);
        float Z = bsum256(e0 + e1 + e2 + e3, red);
        float2 st0 = stats[(b << 10) + 4 * t];
        float2 st1 = stats[(b << 10) + 4 * t + 1];
        float2 st2 = stats[(b << 10) + 4 * t + 2];
        float2 st3 = stats[(b << 10) + 4 * t + 3];
        float q0v = (e0 / Z) * st0.y, q1v = (e1 / Z) * st1.y;
        float q2v = (e2 / Z) * st2.y, q3v = (e3 / Z) * st3.y;
        float c1p = q0v * st0.x + q1v * st1.x + q2v * st2.x + q3v * st3.x;
        float c1t = bsum256(c1p, red);
        float4 o4; o4.x = q0v; o4.y = q1v; o4.z = q2v; o4.w = q3v;
        ((float4*)(qb + ((size_t)bid << 10)))[t] = o4;
        if (t == 0) c1w[bid] = c1t;
    }
    grid.sync();

    // ============ S3: wsum partials (all 256 blocks, 32-row chunks) ============
    {
        int b = bid & 7, jc = bid >> 3;
        if (t < 128) {
            int h = t >> 3, j4 = (t & 7) * 4;
            float4 pv = *(const float4*)(qb + (((size_t)b * 16 + h) << 10) + jc * 32 + j4);
            qs_s[h][j4] = pv.x; qs_s[h][j4 + 1] = pv.y;
            qs_s[h][j4 + 2] = pv.z; qs_s[h][j4 + 3] = pv.w;
        }
        __syncthreads();
        float acc[16][3];
#pragma unroll
        for (int h = 0; h < 16; ++h) { acc[h][0] = 0.f; acc[h][1] = 0.f; acc[h][2] = 0.f; }
        int j0 = jc * 32;
        const float* sp0 = j0 ? (tf + ((size_t)b * 1023 + (j0 - 1)) * 768) : clsT;
        float nx0 = sp0[t], nx1 = sp0[t + 256], nx2 = sp0[t + 512];
        for (int jj = 0; jj < 32; ++jj) {
            float x0 = nx0, x1 = nx1, x2 = nx2;
            if (jj < 31) {
                const float* sp = tf + ((size_t)b * 1023 + j0 + jj) * 768;
                nx0 = sp[t]; nx1 = sp[t + 256]; nx2 = sp[t + 512];
            }
#pragma unroll
            for (int h = 0; h < 16; ++h) {
                float qh = qs_s[h][jj];
                acc[h][0] = fmaf(qh, x0, acc[h][0]);
                acc[h][1] = fmaf(qh, x1, acc[h][1]);
                acc[h][2] = fmaf(qh, x2, acc[h][2]);
            }
        }
        float* o = up + (((size_t)b * 32 + jc) * 16) * 768;
#pragma unroll
        for (int h = 0; h < 16; ++h) {
            o[h * 768 + t] = acc[h][0];
            o[h * 768 + t + 256] = acc[h][1];
            o[h * 768 + t + 512] = acc[h][2];
        }
    }
    grid.sync();

    // ============ S4: o0 = (ga⊙(wsum−c1)+gb) @ Wv_h + bv (blocks < 128) ============
    if (bid < 128) {
        int h = bid & 15, b = bid >> 4;
        float s0 = 0.f, s1 = 0.f, s2 = 0.f;
#pragma unroll 8
        for (int jc = 0; jc < 32; ++jc) {
            const float* q = up + (((size_t)b * 32 + jc) * 16 + h) * 768;
            s0 += q[t]; s1 += q[t + 256]; s2 += q[t + 512];
        }
        float c1 = c1w[b * 16 + h];
        us[t]       = ln1a[t] * (s0 - c1) + ln1b[t];
        us[t + 256] = ln1a[t + 256] * (s1 - c1) + ln1b[t + 256];
        us[t + 512] = ln1a[t + 512] * (s2 - c1) + ln1b[t + 512];
        __syncthreads();
        int dd = t & 63, kg = t >> 6;
        float a = 0.f;
        if (dd < 48) {
#pragma unroll 8
            for (int i = 0; i < 192; ++i) {
                int k = kg * 192 + i;
                a = fmaf(us[k], Wv[(size_t)k * 768 + h * 48 + dd], a);
            }
        }
        part64[kg][dd] = a;
        __syncthreads();
        if (t < 48)
            o0[(size_t)b * 768 + h * 48 + t] =
                part64[0][t] + part64[1][t] + part64[2][t] + part64[3][t] + bv[h * 48 + t];
    }
    grid.sync();

    // ============ S5: x2 = clsT + o0 @ Wo + bo (blocks < 96) ============
    if (bid < 96) {
        int cb = bid >> 3, b = bid & 7;
        const float* xr = o0 + (size_t)b * 768;
        ys[t] = xr[t]; ys[t + 256] = xr[t + 256]; ys[t + 512] = xr[t + 512];
        __syncthreads();
        int c = cb * 64 + (t & 15) * 4;
        int kq = t >> 4;
        float4 acc = {0.f, 0.f, 0.f, 0.f};
#pragma unroll 8
        for (int i = 0; i < 48; ++i) {
            int k = kq * 48 + i;
            float4 wv = *(const float4*)&Wo[(size_t)k * 768 + c];
            float y = ys[k];
            acc.x = fmaf(y, wv.x, acc.x); acc.y = fmaf(y, wv.y, acc.y);
            acc.z = fmaf(y, wv.z, acc.z); acc.w = fmaf(y, wv.w, acc.w);
        }
        part16[kq][t & 15] = acc;
        __syncthreads();
        if (t < 16) {
            float4 s = {0.f, 0.f, 0.f, 0.f};
#pragma unroll
            for (int i = 0; i < 16; ++i) {
                float4 v = part16[i][t];
                s.x += v.x; s.y += v.y; s.z += v.z; s.w += v.w;
            }
            int cc = cb * 64 + t * 4;
            float4 b4 = *(const float4*)&bo[cc];
            float4 r4 = *(const float4*)&clsT[cc];
            float* o = x2w + (size_t)b * 768 + cc;
            o[0] = s.x + b4.x + r4.x; o[1] = s.y + b4.y + r4.y;
            o[2] = s.z + b4.z + r4.z; o[3] = s.w + b4.w + r4.w;
        }
    }
    grid.sync();

    // ============ S6: f1 = relu(LN2(x2) @ W1 + b1) (blocks < 192) ============
    if (bid < 192) {
        int cb = bid >> 3, b = bid & 7;
        const float* xr = x2w + (size_t)b * 768;
        float a0 = xr[t], a1 = xr[t + 256], a2 = xr[t + 512];
        float mean = bsum256(a0 + a1 + a2, red) * (1.0f / 768.0f);
        float d0 = a0 - mean, d1 = a1 - mean, d2 = a2 - mean;
        float var = bsum256(d0 * d0 + d1 * d1 + d2 * d2, red) * (1.0f / 767.0f);
        float den = sqrtf(var) + 1e-6f;
        ys[t]       = (ln2a[t] * d0) / den + ln2b[t];
        ys[t + 256] = (ln2a[t + 256] * d1) / den + ln2b[t + 256];
        ys[t + 512] = (ln2a[t + 512] * d2) / den + ln2b[t + 512];
        __syncthreads();
        int c = cb * 128 + (t & 31) * 4;
        int kq = t >> 5;
        float4 acc = {0.f, 0.f, 0.f, 0.f};
#pragma unroll 8
        for (int i = 0; i < 96; ++i) {
            int k = kq * 96 + i;
            float4 wv = *(const float4*)&W1[(size_t)k * 3072 + c];
            float y = ys[k];
            acc.x = fmaf(y, wv.x, acc.x); acc.y = fmaf(y, wv.y, acc.y);
            acc.z = fmaf(y, wv.z, acc.z); acc.w = fmaf(y, wv.w, acc.w);
        }
        part8[kq][t & 31] = acc;
        __syncthreads();
        if (t < 32) {
            float4 s = {0.f, 0.f, 0.f, 0.f};
#pragma unroll
            for (int i = 0; i < 8; ++i) {
                float4 v = part8[i][t];
                s.x += v.x; s.y += v.y; s.z += v.z; s.w += v.w;
            }
            int cc = cb * 128 + t * 4;
            float4 b4 = *(const float4*)&b1[cc];
            float* o = f1w + (size_t)b * 3072 + cc;
            o[0] = fmaxf(s.x + b4.x, 0.f); o[1] = fmaxf(s.y + b4.y, 0.f);
            o[2] = fmaxf(s.z + b4.z, 0.f); o[3] = fmaxf(s.w + b4.w, 0.f);
        }
    }
    grid.sync();

    // ============ S7: x3 = x2 + f1 @ W2 + b2 (blocks < 96) ============
    if (bid < 96) {
        int cb = bid >> 3, b = bid & 7;
        const float* xr = f1w + (size_t)b * 3072;
        for (int i = t; i < 3072; i += 256) ys[i] = xr[i];
        __syncthreads();
        int c = cb * 64 + (t & 15) * 4;
        int kq = t >> 4;
        float4 acc = {0.f, 0.f, 0.f, 0.f};
#pragma unroll 8
        for (int i = 0; i < 192; ++i) {
            int k = kq * 192 + i;
            float4 wv = *(const float4*)&W2[(size_t)k * 768 + c];
            float y = ys[k];
            acc.x = fmaf(y, wv.x, acc.x); acc.y = fmaf(y, wv.y, acc.y);
            acc.z = fmaf(y, wv.z, acc.z); acc.w = fmaf(y, wv.w, acc.w);
        }
        part16[kq][t & 15] = acc;
        __syncthreads();
        if (t < 16) {
            float4 s = {0.f, 0.f, 0.f, 0.f};
#pragma unroll
            for (int i = 0; i < 16; ++i) {
                float4 v = part16[i][t];
                s.x += v.x; s.y += v.y; s.z += v.z; s.w += v.w;
            }
            int cc = cb * 64 + t * 4;
            float4 b4 = *(const float4*)&b2[cc];
            const float* x2r = x2w + (size_t)b * 768 + cc;
            float* o = x3w + (size_t)b * 768 + cc;
            o[0] = x2r[0] + s.x + b4.x; o[1] = x2r[1] + s.y + b4.y;
            o[2] = x2r[2] + s.z + b4.z; o[3] = x2r[3] + s.w + b4.w;
        }
    }
    grid.sync();

    // ============ S8: head logit partials in double (blocks < 64) ============
    if (bid < 64) {
        int kg = bid >> 3, b = bid & 7;
        const float* xr = x3w + (size_t)b * 768;
        float a0 = xr[t], a1 = xr[t + 256], a2 = xr[t + 512];
        float mean = bsum256(a0 + a1 + a2, red) * (1.0f / 768.0f);
        float d0 = a0 - mean, d1 = a1 - mean, d2 = a2 - mean;
        float var = bsum256(d0 * d0 + d1 * d1 + d2 * d2, red) * (1.0f / 767.0f);
        float den = sqrtf(var) + 1e-6f;
        ys[t]       = (lnfa[t] * d0) / den + lnfb[t];
        ys[t + 256] = (lnfa[t + 256] * d1) / den + lnfb[t + 256];
        ys[t + 512] = (lnfa[t + 512] * d2) / den + lnfb[t + 512];
        __syncthreads();
        int kbase = kg * 96;
        if (t < 100) {
            double a = 0.0;
#pragma unroll 8
            for (int i = 0; i < 96; ++i) {
                int k = kbase + i;
                a = fma((double)ys[k], (double)Wpool[k * 100 + t], a);
            }
            lp[((size_t)b * 8 + kg) * 112 + t] = a;
        } else if (t < 107) {
            int c = t - 100;
            double a = 0.0;
#pragma unroll 8
            for (int i = 0; i < 96; ++i) {
                int k = kbase + i;
                a = fma((double)ys[k], (double)Wcls[k * 7 + c], a);
            }
            lp[((size_t)b * 8 + kg) * 112 + t] = a;
        }
    }
    grid.sync();

    // ============ S9: decide (blocks < 8) ============
    if (bid < 8) {
        int b = bid;
        if (t < 107) {
            double a = (t < 100) ? (double)bpool[t] : (double)bcls[t - 100];
#pragma unroll
            for (int kg = 0; kg < 8; ++kg) a += lp[((size_t)b * 8 + kg) * 112 + t];
            if (t < 100) sPd[t] = a;
            else {
                sC7d[t - 100] = a;
                out[OUT_CLS_OFF + b * 7 + (t - 100)] = (float)a;
            }
        }
        __syncthreads();
        double mx = sPd[0];
        for (int j = 1; j < 100; ++j) mx = fmax(mx, sPd[j]);
        double e = (t < 100) ? exp(sPd[t] - mx) : 0.0;
        __syncthreads();
        if (t < 100) sPd[t] = e;
        __syncthreads();
        double zs = 0.0;
        for (int j = 0; j < 100; ++j) zs += sPd[j];
        __syncthreads();
        if (t < 100) sPd[t] = e / zs;
        __syncthreads();
        if (t == 0) {
            double m7 = sC7d[0];
            for (int j = 1; j < 7; ++j) m7 = fmax(m7, sC7d[j]);
            double es[7]; double z = 0.0;
            for (int j = 0; j < 7; ++j) { es[j] = exp(sC7d[j] - m7); z += es[j]; }
            double ent = 0.0;
            for (int j = 0; j < 7; ++j) { double pr = es[j] / z; ent -= pr * log(pr + 1e-9); }
            double ne = ent / log(7.0);
            int kk = (int)floor(1.0 + ne * 99.0);
            kkw[b] = kk < 1 ? 1 : (kk > 100 ? 100 : kk);
        }
        if (t < 100) {
            double pi = sPd[t];
            int r = 0;
            for (int j = 0; j < 100; ++j) {
                double pj = sPd[j];
                r += (pj > pi) || (pj == pi && j < t);
            }
            topw[b * 100 + r] = t;   // descending, stable
        }
    }
    grid.sync();

    // ============ S10: gather (all blocks) ============
    for (int i = bid; i < 800; i += 256) {
        int b = i & 7, r = i >> 3;
        int idx = topw[b * 100 + r];
        bool keep = r < kkw[b];
        if (t < 192) {
            const float4* src = (const float4*)(pool + (size_t)idx * 768);
            float4* dst = (float4*)(out + (size_t)b * 76800 + (size_t)r * 768);
            float4 z = {0.f, 0.f, 0.f, 0.f};
            dst[t] = keep ? src[t] : z;
        }
    }
}

// ---------------------------------------------------------------------------
extern "C" void kernel_launch(void* const* d_in, const int* in_sizes, int n_in,
                              void* d_out, int out_size, void* d_ws, size_t ws_size,
                              hipStream_t stream) {
    (void)in_sizes; (void)n_in; (void)out_size; (void)ws_size;
    const float* tf    = (const float*)d_in[0];
    const float* pool  = (const float*)d_in[1];
    const float* clsT  = (const float*)d_in[2];
    const float* Wq    = (const float*)d_in[3];
    const float* bq    = (const float*)d_in[4];
    const float* Wk    = (const float*)d_in[5];
    const float* bk    = (const float*)d_in[6];
    const float* Wv    = (const float*)d_in[7];
    const float* bv    = (const float*)d_in[8];
    const float* Wo    = (const float*)d_in[9];
    const float* bo    = (const float*)d_in[10];
    const float* ln1a  = (const float*)d_in[11];
    const float* ln1b  = (const float*)d_in[12];
    const float* ln2a  = (const float*)d_in[13];
    const float* ln2b  = (const float*)d_in[14];
    const float* W1    = (const float*)d_in[15];
    const float* b1    = (const float*)d_in[16];
    const float* W2    = (const float*)d_in[17];
    const float* b2    = (const float*)d_in[18];
    const float* lnfa  = (const float*)d_in[19];
    const float* lnfb  = (const float*)d_in[20];
    const float* Wpool = (const float*)d_in[21];
    const float* bpool = (const float*)d_in[22];
    const float* Wcls  = (const float*)d_in[23];
    const float* bcls  = (const float*)d_in[24];
    float* out = (float*)d_out;
    char* ws = (char*)d_ws;

    float*  sc    = (float*)(ws + 0);           // 524,288
    float*  qb    = (float*)(ws + 524288);      // 524,288
    float2* stats = (float2*)(ws + 1048576);    // 65,536
    float*  wkqc  = (float*)(ws + 1114112);     // 49,408
    float*  q0    = (float*)(ws + 1163520);     // 3,072
    float*  colw  = (float*)(ws + 1166592);     // 6,144
    float*  c1w   = (float*)(ws + 1172736);     // 512
    float*  up    = (float*)(ws + 1173248);     // 12,582,912
    float*  o0    = (float*)(ws + 13756160);    // 24,576
    float*  x2w   = (float*)(ws + 13780736);    // 24,576
    float*  f1w   = (float*)(ws + 13805312);    // 98,304
    float*  x3w   = (float*)(ws + 13903616);    // 24,576
    int*    topw  = (int*)(ws + 13928192);      // 3,200
    int*    kkw   = (int*)(ws + 13931392);      // 32
    double* lp    = (double*)(ws + 13931424);   // 57,344  (total ~14 MB)

    prep_a<<<24, 256, 0, stream>>>(clsT, ln1a, ln1b, Wq, bq, Wk, q0, colw);
    prep_b<<<48, 256, 0, stream>>>(Wk, bk, q0, colw, wkqc);

    void* ka[] = { &tf, &clsT, &ln1a, &ln1b, &wkqc, &sc, &stats, &qb, &c1w, &up,
                   &Wv, &bv, &o0, &Wo, &bo, &x2w, &ln2a, &ln2b, &W1, &b1, &f1w,
                   &W2, &b2, &x3w, &lnfa, &lnfb, &Wpool, &Wcls, &lp, &bpool,
                   &bcls, &pool, &out, &topw, &kkw };
    hipLaunchCooperativeKernel(reinterpret_cast<void*>(fused_k),
                               dim3(256), dim3(256), ka, 0, stream);
}

// Round 8
// 261.471 us; speedup vs baseline: 1.3960x; 1.3960x over previous
//
#include <hip/hip_runtime.h>

// ---------------------------------------------------------------------------
// PromptSelector — collapsed algebra, 9 launches.
//   scores[b,h,j] = rden_j*(dot(ga*x_j, wk[:,h]) - mean_j*Sgw[h]) + CgbC[h]
//   u[b,h,:] = ga ⊙ (Σ_j q_j x_j − c1) + gb,   q_j = p_j·rden_j, c1 = Σ q_j·mean_j
// Round 8: round-6 multi-kernel structure (round-7 coop fusion was 3.3x slower:
// 1 block/CU starved the streaming phases). Softmax fused into scores_sm and
// logits+decide fused into x3ld_k via last-block device-scope atomics.
// ---------------------------------------------------------------------------

#define OUT_CLS_OFF 614400   // 8*100*768

__device__ __forceinline__ float bsum256(float v, float* red) {
    int lane = threadIdx.x & 63, w = threadIdx.x >> 6;
#pragma unroll
    for (int off = 1; off < 64; off <<= 1) v += __shfl_xor(v, off);
    __syncthreads();
    if (lane == 0) red[w] = v;
    __syncthreads();
    return red[0] + red[1] + red[2] + red[3];
}
__device__ __forceinline__ float bmax256(float v, float* red) {
    int lane = threadIdx.x & 63, w = threadIdx.x >> 6;
#pragma unroll
    for (int off = 1; off < 64; off <<= 1) v = fmaxf(v, __shfl_xor(v, off));
    __syncthreads();
    if (lane == 0) red[w] = v;
    __syncthreads();
    return fmaxf(fmaxf(red[0], red[1]), fmaxf(red[2], red[3]));
}

// ---------------------------------------------------------------------------
// prep_a: blocks 0-11 -> q0 = LN1(cls) @ Wq + bq; blocks 12-23 -> colga/colgb
// (ga/gb-weighted column sums of Wk). Block 0 also zeroes the phase counters.
__global__ __launch_bounds__(256) void prep_a(
    const float* __restrict__ clsT, const float* __restrict__ ga,
    const float* __restrict__ gb, const float* __restrict__ Wq,
    const float* __restrict__ bq, const float* __restrict__ Wk,
    float* __restrict__ q0, float* __restrict__ colw, int* __restrict__ cnts)
{
    __shared__ float ys[768];
    __shared__ float red[4];
    __shared__ float4 partA[16][17];
    __shared__ float4 partB[16][17];
    int t = threadIdx.x;
    if (blockIdx.x == 0 && t < 16) cnts[t] = 0;
    if (blockIdx.x < 12) {
        float a0 = clsT[t], a1 = clsT[t + 256], a2 = clsT[t + 512];
        float mean = bsum256(a0 + a1 + a2, red) * (1.0f / 768.0f);
        float d0 = a0 - mean, d1 = a1 - mean, d2 = a2 - mean;
        float var = bsum256(d0 * d0 + d1 * d1 + d2 * d2, red) * (1.0f / 767.0f);
        float den = sqrtf(var) + 1e-6f;
        ys[t]       = (ga[t] * d0) / den + gb[t];
        ys[t + 256] = (ga[t + 256] * d1) / den + gb[t + 256];
        ys[t + 512] = (ga[t + 512] * d2) / den + gb[t + 512];
        __syncthreads();
        int c = blockIdx.x * 64 + (t & 15) * 4;
        int kq = t >> 4;
        float4 acc = {0.f, 0.f, 0.f, 0.f};
#pragma unroll 8
        for (int i = 0; i < 48; ++i) {
            int k = kq * 48 + i;
            float4 w = *(const float4*)&Wq[(size_t)k * 768 + c];
            float y = ys[k];
            acc.x = fmaf(y, w.x, acc.x); acc.y = fmaf(y, w.y, acc.y);
            acc.z = fmaf(y, w.z, acc.z); acc.w = fmaf(y, w.w, acc.w);
        }
        partA[kq][t & 15] = acc;
        __syncthreads();
        if (t < 16) {
            float4 s = {0.f, 0.f, 0.f, 0.f};
#pragma unroll
            for (int i = 0; i < 16; ++i) {
                float4 v = partA[i][t];
                s.x += v.x; s.y += v.y; s.z += v.z; s.w += v.w;
            }
            int cc = blockIdx.x * 64 + t * 4;
            float4 b4 = *(const float4*)&bq[cc];
            q0[cc] = s.x + b4.x; q0[cc + 1] = s.y + b4.y;
            q0[cc + 2] = s.z + b4.z; q0[cc + 3] = s.w + b4.w;
        }
    } else {
        int c = (blockIdx.x - 12) * 64 + (t & 15) * 4;
        int kq = t >> 4;
        float4 aa = {0.f, 0.f, 0.f, 0.f}, ab = {0.f, 0.f, 0.f, 0.f};
#pragma unroll 8
        for (int i = 0; i < 48; ++i) {
            int k = kq * 48 + i;
            float4 w = *(const float4*)&Wk[(size_t)k * 768 + c];
            float g = ga[k], h = gb[k];
            aa.x = fmaf(g, w.x, aa.x); aa.y = fmaf(g, w.y, aa.y);
            aa.z = fmaf(g, w.z, aa.z); aa.w = fmaf(g, w.w, aa.w);
            ab.x = fmaf(h, w.x, ab.x); ab.y = fmaf(h, w.y, ab.y);
            ab.z = fmaf(h, w.z, ab.z); ab.w = fmaf(h, w.w, ab.w);
        }
        partA[kq][t & 15] = aa;
        partB[kq][t & 15] = ab;
        __syncthreads();
        if (t < 16) {
            float4 sa = {0.f, 0.f, 0.f, 0.f}, sb = {0.f, 0.f, 0.f, 0.f};
#pragma unroll
            for (int i = 0; i < 16; ++i) {
                float4 va = partA[i][t], vb = partB[i][t];
                sa.x += va.x; sa.y += va.y; sa.z += va.z; sa.w += va.w;
                sb.x += vb.x; sb.y += vb.y; sb.z += vb.z; sb.w += vb.w;
            }
            int cc = (blockIdx.x - 12) * 64 + t * 4;
            *(float4*)&colw[cc] = sa;
            *(float4*)&colw[768 + cc] = sb;
        }
    }
}

// ---------------------------------------------------------------------------
// prep_b: wkq[k][h] = (Wk[k,h48..] . q0_h)/sqrt(48); block 0 also computes
// Sgw[h] (at 12304) and CgbC[h] (at 12320) from colga/colgb + bk.
__global__ __launch_bounds__(256) void prep_b(
    const float* __restrict__ Wk, const float* __restrict__ bk,
    const float* __restrict__ q0, const float* __restrict__ colw,
    float* __restrict__ wkqc)
{
    __shared__ float qs[768];
    int t = threadIdx.x;
    qs[t] = q0[t]; qs[t + 256] = q0[t + 256]; qs[t + 512] = q0[t + 512];
    __syncthreads();
    const float invs = 0.14433756729740643f;  // 1/sqrt(48)
    int kl = t >> 4, h = t & 15;
    int k = blockIdx.x * 16 + kl;
    const float* wr = Wk + (size_t)k * 768 + h * 48;
    const float* qh = qs + h * 48;
    float a = 0.f;
#pragma unroll
    for (int d = 0; d < 48; d += 4) {
        float4 w = *(const float4*)&wr[d];
        a += w.x * qh[d] + w.y * qh[d + 1] + w.z * qh[d + 2] + w.w * qh[d + 3];
    }
    wkqc[k * 16 + h] = a * invs;
    if (blockIdx.x == 0 && t < 16) {
        float cd = 0.f, sa = 0.f, sb = 0.f;
        for (int d = 0; d < 48; ++d) {
            int dd = t * 48 + d;
            cd = fmaf(bk[dd], qs[dd], cd);
            sa = fmaf(colw[dd], qs[dd], sa);
            sb = fmaf(colw[768 + dd], qs[dd], sb);
        }
        wkqc[12304 + t] = sa * invs;
        wkqc[12320 + t] = sb * invs + cd * invs;
    }
}

// ---------------------------------------------------------------------------
// scores + fused per-batch softmax. grid 1024 (8 rows/block; 128 blocks/batch).
// Last block of each batch (device-scope counter) computes softmax for the 16
// heads, emitting qb = p*rden and c1 = sum q*mean. Deterministic: one block,
// fixed order, regardless of which block is last.
__global__ __launch_bounds__(256) void scores_sm(
    const float* __restrict__ tf, const float* __restrict__ clsT,
    const float* __restrict__ ga, const float* __restrict__ wkqc,
    float* __restrict__ sc, float2* __restrict__ stats,
    float* __restrict__ qb, float* __restrict__ c1w, int* __restrict__ cnt_sc)
{
    __shared__ float tr[256][17];
    __shared__ float partw[4][16];
    __shared__ float redw[2][4][2];
    __shared__ float red[4];
    __shared__ int sOld;
    int t = threadIdx.x;
    int l = t & 63, w = t >> 6;

    float wk0[16], wk1[16], wk2[16];
    {
        const float4* p0 = (const float4*)(wkqc + t * 16);
        const float4* p1 = (const float4*)(wkqc + (t + 256) * 16);
        const float4* p2 = (const float4*)(wkqc + (t + 512) * 16);
#pragma unroll
        for (int q = 0; q < 4; ++q) {
            float4 v0 = p0[q], v1 = p1[q], v2 = p2[q];
            wk0[q * 4] = v0.x; wk0[q * 4 + 1] = v0.y; wk0[q * 4 + 2] = v0.z; wk0[q * 4 + 3] = v0.w;
            wk1[q * 4] = v1.x; wk1[q * 4 + 1] = v1.y; wk1[q * 4 + 2] = v1.z; wk1[q * 4 + 3] = v1.w;
            wk2[q * 4] = v2.x; wk2[q * 4 + 1] = v2.y; wk2[q * 4 + 2] = v2.z; wk2[q * 4 + 3] = v2.w;
        }
    }
    float ga0 = ga[t], ga1 = ga[t + 256], ga2 = ga[t + 512];
    float Sgv = wkqc[12304 + (t & 15)];
    float Cgv = wkqc[12320 + (t & 15)];

    int r0 = blockIdx.x * 8;
    int b = r0 >> 10;
    for (int r = 0; r < 8; ++r) {
        int row = r0 + r;
        int j = row & 1023;
        const float* src = j ? (tf + ((size_t)b * 1023 + (j - 1)) * 768) : clsT;
        float x0 = src[t], x1 = src[t + 256], x2 = src[t + 512];
        float s1 = x0 + x1 + x2;
        float s2 = fmaf(x0, x0, fmaf(x1, x1, x2 * x2));
        float g0 = ga0 * x0, g1 = ga1 * x1, g2 = ga2 * x2;
        float dt[16];
#pragma unroll
        for (int h = 0; h < 16; ++h)
            dt[h] = fmaf(g0, wk0[h], fmaf(g1, wk1[h], g2 * wk2[h]));
#pragma unroll
        for (int off = 1; off < 64; off <<= 1) {
            s1 += __shfl_xor(s1, off);
            s2 += __shfl_xor(s2, off);
        }
        if (l == 0) { redw[r & 1][w][0] = s1; redw[r & 1][w][1] = s2; }
#pragma unroll
        for (int h = 0; h < 16; ++h) tr[t][h] = dt[h];
        __syncthreads();
        int hh = t & 15, ch = t >> 4;
        float v = 0.f;
#pragma unroll
        for (int i = 0; i < 16; ++i) v += tr[ch * 16 + i][hh];
        v += __shfl_xor(v, 16);
        v += __shfl_xor(v, 32);
        if (l < 16) partw[w][l] = v;
        __syncthreads();
        if (t < 16) {
            float dtot = partw[0][t] + partw[1][t] + partw[2][t] + partw[3][t];
            float s1t = redw[r & 1][0][0] + redw[r & 1][1][0] + redw[r & 1][2][0] + redw[r & 1][3][0];
            float s2t = redw[r & 1][0][1] + redw[r & 1][1][1] + redw[r & 1][2][1] + redw[r & 1][3][1];
            float mean = s1t * (1.0f / 768.0f);
            float var = (s2t - mean * s1t) * (1.0f / 767.0f);
            float rden = 1.0f / (sqrtf(var) + 1e-6f);
            sc[(((size_t)b * 16 + t) << 10) + j] = rden * (dtot - mean * Sgv) + Cgv;
            if (t == 0) stats[(b << 10) + j] = make_float2(mean, rden);
        }
    }

    // ---- last-block softmax for this batch ----
    __threadfence();
    if (t == 0)
        sOld = __hip_atomic_fetch_add(&cnt_sc[b], 1, __ATOMIC_ACQ_REL,
                                      __HIP_MEMORY_SCOPE_AGENT);
    __syncthreads();
    if (sOld != 127) return;

    float2 st0 = stats[(b << 10) + 4 * t];
    float2 st1 = stats[(b << 10) + 4 * t + 1];
    float2 st2 = stats[(b << 10) + 4 * t + 2];
    float2 st3 = stats[(b << 10) + 4 * t + 3];
    for (int h = 0; h < 16; ++h) {
        const float4* s4 = (const float4*)(sc + (((size_t)b * 16 + h) << 10));
        float4 v = s4[t];
        float m = fmaxf(fmaxf(v.x, v.y), fmaxf(v.z, v.w));
        float M = bmax256(m, red);
        float e0 = expf(v.x - M), e1 = expf(v.y - M), e2 = expf(v.z - M), e3 = expf(v.w - M);
        float Z = bsum256(e0 + e1 + e2 + e3, red);
        float q0v = (e0 / Z) * st0.y, q1v = (e1 / Z) * st1.y;
        float q2v = (e2 / Z) * st2.y, q3v = (e3 / Z) * st3.y;
        float c1t = bsum256(q0v * st0.x + q1v * st1.x + q2v * st2.x + q3v * st3.x, red);
        float4 o4; o4.x = q0v; o4.y = q1v; o4.z = q2v; o4.w = q3v;
        ((float4*)(qb + (((size_t)b * 16 + h) << 10)))[t] = o4;
        if (t == 0) c1w[b * 16 + h] = c1t;
    }
}

// ---------------------------------------------------------------------------
// wsum partials: up[b][jc][h][:] = Σ_j qb*x over 32-row chunk. grid 256.
__global__ __launch_bounds__(256) void upart_k(
    const float* __restrict__ tf, const float* __restrict__ clsT,
    const float* __restrict__ qb, float* __restrict__ up)
{
    __shared__ float qs_s[16][32];
    int b = blockIdx.x & 7, jc = blockIdx.x >> 3;
    int t = threadIdx.x;
    if (t < 128) {
        int h = t >> 3, j4 = (t & 7) * 4;
        float4 pv = *(const float4*)(qb + (((size_t)b * 16 + h) << 10) + jc * 32 + j4);
        qs_s[h][j4] = pv.x; qs_s[h][j4 + 1] = pv.y;
        qs_s[h][j4 + 2] = pv.z; qs_s[h][j4 + 3] = pv.w;
    }
    __syncthreads();
    float acc[16][3];
#pragma unroll
    for (int h = 0; h < 16; ++h) { acc[h][0] = 0.f; acc[h][1] = 0.f; acc[h][2] = 0.f; }
    int j0 = jc * 32;
    const float* sp0 = j0 ? (tf + ((size_t)b * 1023 + (j0 - 1)) * 768) : clsT;
    float nx0 = sp0[t], nx1 = sp0[t + 256], nx2 = sp0[t + 512];
    for (int jj = 0; jj < 32; ++jj) {
        float x0 = nx0, x1 = nx1, x2 = nx2;
        if (jj < 31) {
            const float* sp = tf + ((size_t)b * 1023 + j0 + jj) * 768;
            nx0 = sp[t]; nx1 = sp[t + 256]; nx2 = sp[t + 512];
        }
#pragma unroll
        for (int h = 0; h < 16; ++h) {
            float qh = qs_s[h][jj];
            acc[h][0] = fmaf(qh, x0, acc[h][0]);
            acc[h][1] = fmaf(qh, x1, acc[h][1]);
            acc[h][2] = fmaf(qh, x2, acc[h][2]);
        }
    }
    float* o = up + (((size_t)b * 32 + jc) * 16) * 768;
#pragma unroll
    for (int h = 0; h < 16; ++h) {
        o[h * 768 + t] = acc[h][0];
        o[h * 768 + t + 256] = acc[h][1];
        o[h * 768 + t + 512] = acc[h][2];
    }
}

// ---------------------------------------------------------------------------
// o0 = (ga⊙(wsum−c1)+gb) @ Wv_h + bv. grid (16 h, 8 b).
__global__ __launch_bounds__(256) void o0_k(
    const float* __restrict__ up, const float* __restrict__ c1w,
    const float* __restrict__ ga, const float* __restrict__ gb,
    const float* __restrict__ Wv, const float* __restrict__ bv,
    float* __restrict__ o0)
{
    __shared__ float us[768];
    __shared__ float part[4][64];
    int h = blockIdx.x, b = blockIdx.y, t = threadIdx.x;
    float s0 = 0.f, s1 = 0.f, s2 = 0.f;
#pragma unroll 8
    for (int jc = 0; jc < 32; ++jc) {
        const float* q = up + (((size_t)b * 32 + jc) * 16 + h) * 768;
        s0 += q[t]; s1 += q[t + 256]; s2 += q[t + 512];
    }
    float c1 = c1w[b * 16 + h];
    us[t]       = ga[t] * (s0 - c1) + gb[t];
    us[t + 256] = ga[t + 256] * (s1 - c1) + gb[t + 256];
    us[t + 512] = ga[t + 512] * (s2 - c1) + gb[t + 512];
    __syncthreads();
    int dd = t & 63, kg = t >> 6;
    float a = 0.f;
    if (dd < 48) {
#pragma unroll 8
        for (int i = 0; i < 192; ++i) {
            int k = kg * 192 + i;
            a = fmaf(us[k], Wv[(size_t)k * 768 + h * 48 + dd], a);
        }
    }
    part[kg][dd] = a;
    __syncthreads();
    if (t < 48)
        o0[(size_t)b * 768 + h * 48 + t] =
            part[0][t] + part[1][t] + part[2][t] + part[3][t] + bv[h * 48 + t];
}

// ---------------------------------------------------------------------------
// x2 = clsT + o0 @ Wo + bo. grid (12, 8).
__global__ __launch_bounds__(256) void x2_k(
    const float* __restrict__ o0, const float* __restrict__ Wo,
    const float* __restrict__ bo, const float* __restrict__ clsT,
    float* __restrict__ x2w)
{
    __shared__ float ys[768];
    __shared__ float4 part[16][17];
    int b = blockIdx.y, t = threadIdx.x;
    const float* xr = o0 + (size_t)b * 768;
    ys[t] = xr[t]; ys[t + 256] = xr[t + 256]; ys[t + 512] = xr[t + 512];
    __syncthreads();
    int c = blockIdx.x * 64 + (t & 15) * 4;
    int kq = t >> 4;
    float4 acc = {0.f, 0.f, 0.f, 0.f};
#pragma unroll 8
    for (int i = 0; i < 48; ++i) {
        int k = kq * 48 + i;
        float4 w = *(const float4*)&Wo[(size_t)k * 768 + c];
        float y = ys[k];
        acc.x = fmaf(y, w.x, acc.x); acc.y = fmaf(y, w.y, acc.y);
        acc.z = fmaf(y, w.z, acc.z); acc.w = fmaf(y, w.w, acc.w);
    }
    part[kq][t & 15] = acc;
    __syncthreads();
    if (t < 16) {
        float4 s = {0.f, 0.f, 0.f, 0.f};
#pragma unroll
        for (int i = 0; i < 16; ++i) {
            float4 v = part[i][t];
            s.x += v.x; s.y += v.y; s.z += v.z; s.w += v.w;
        }
        int cc = blockIdx.x * 64 + t * 4;
        float4 b4 = *(const float4*)&bo[cc];
        float4 r4 = *(const float4*)&clsT[cc];
        float* o = x2w + (size_t)b * 768 + cc;
        o[0] = s.x + b4.x + r4.x; o[1] = s.y + b4.y + r4.y;
        o[2] = s.z + b4.z + r4.z; o[3] = s.w + b4.w + r4.w;
    }
}

// ---------------------------------------------------------------------------
// f1 = relu(LN2(x2) @ W1 + b1), LN fused. grid (24, 8).
__global__ __launch_bounds__(256) void f1_k(
    const float* __restrict__ x2w, const float* __restrict__ ga,
    const float* __restrict__ gb, const float* __restrict__ W1,
    const float* __restrict__ b1, float* __restrict__ f1w)
{
    __shared__ float ys[768];
    __shared__ float red[4];
    __shared__ float4 part[8][33];
    int b = blockIdx.y, t = threadIdx.x;
    const float* xr = x2w + (size_t)b * 768;
    float a0 = xr[t], a1 = xr[t + 256], a2 = xr[t + 512];
    float mean = bsum256(a0 + a1 + a2, red) * (1.0f / 768.0f);
    float d0 = a0 - mean, d1 = a1 - mean, d2 = a2 - mean;
    float var = bsum256(d0 * d0 + d1 * d1 + d2 * d2, red) * (1.0f / 767.0f);
    float den = sqrtf(var) + 1e-6f;
    ys[t]       = (ga[t] * d0) / den + gb[t];
    ys[t + 256] = (ga[t + 256] * d1) / den + gb[t + 256];
    ys[t + 512] = (ga[t + 512] * d2) / den + gb[t + 512];
    __syncthreads();
    int c = blockIdx.x * 128 + (t & 31) * 4;
    int kq = t >> 5;
    float4 acc = {0.f, 0.f, 0.f, 0.f};
#pragma unroll 8
    for (int i = 0; i < 96; ++i) {
        int k = kq * 96 + i;
        float4 w = *(const float4*)&W1[(size_t)k * 3072 + c];
        float y = ys[k];
        acc.x = fmaf(y, w.x, acc.x); acc.y = fmaf(y, w.y, acc.y);
        acc.z = fmaf(y, w.z, acc.z); acc.w = fmaf(y, w.w, acc.w);
    }
    part[kq][t & 31] = acc;
    __syncthreads();
    if (t < 32) {
        float4 s = {0.f, 0.f, 0.f, 0.f};
#pragma unroll
        for (int i = 0; i < 8; ++i) {
            float4 v = part[i][t];
            s.x += v.x; s.y += v.y; s.z += v.z; s.w += v.w;
        }
        int cc = blockIdx.x * 128 + t * 4;
        float4 b4 = *(const float4*)&b1[cc];
        float* o = f1w + (size_t)b * 3072 + cc;
        o[0] = fmaxf(s.x + b4.x, 0.f); o[1] = fmaxf(s.y + b4.y, 0.f);
        o[2] = fmaxf(s.z + b4.z, 0.f); o[3] = fmaxf(s.w + b4.w, 0.f);
    }
}

// ---------------------------------------------------------------------------
// x3 = x2 + f1 @ W2 + b2 with fused head: last block per batch does
// LNf + double-precision pool/class logits + entropy + rank. grid (12, 8).
__global__ __launch_bounds__(256) void x3ld_k(
    const float* __restrict__ f1w, const float* __restrict__ W2,
    const float* __restrict__ b2, const float* __restrict__ x2w,
    float* __restrict__ x3w, const float* __restrict__ lnfa,
    const float* __restrict__ lnfb, const float* __restrict__ Wpool,
    const float* __restrict__ Wcls, const float* __restrict__ bpool,
    const float* __restrict__ bcls, float* __restrict__ out,
    int* __restrict__ topw, int* __restrict__ kkw, int* __restrict__ cnt_x3)
{
    __shared__ float ys[3072];
    __shared__ float red[4];
    __shared__ float4 part[16][17];
    __shared__ double sPd[100];
    __shared__ double sC7d[7];
    __shared__ int sOld;
    int b = blockIdx.y, t = threadIdx.x;
    {
        const float* xr = f1w + (size_t)b * 3072;
        for (int i = t; i < 3072; i += 256) ys[i] = xr[i];
        __syncthreads();
        int c = blockIdx.x * 64 + (t & 15) * 4;
        int kq = t >> 4;
        float4 acc = {0.f, 0.f, 0.f, 0.f};
#pragma unroll 8
        for (int i = 0; i < 192; ++i) {
            int k = kq * 192 + i;
            float4 w = *(const float4*)&W2[(size_t)k * 768 + c];
            float y = ys[k];
            acc.x = fmaf(y, w.x, acc.x); acc.y = fmaf(y, w.y, acc.y);
            acc.z = fmaf(y, w.z, acc.z); acc.w = fmaf(y, w.w, acc.w);
        }
        part[kq][t & 15] = acc;
        __syncthreads();
        if (t < 16) {
            float4 s = {0.f, 0.f, 0.f, 0.f};
#pragma unroll
            for (int i = 0; i < 16; ++i) {
                float4 v = part[i][t];
                s.x += v.x; s.y += v.y; s.z += v.z; s.w += v.w;
            }
            int cc = blockIdx.x * 64 + t * 4;
            float4 b4 = *(const float4*)&b2[cc];
            const float* x2r = x2w + (size_t)b * 768 + cc;
            float* o = x3w + (size_t)b * 768 + cc;
            o[0] = x2r[0] + s.x + b4.x; o[1] = x2r[1] + s.y + b4.y;
            o[2] = x2r[2] + s.z + b4.z; o[3] = x2r[3] + s.w + b4.w;
        }
    }
    // ---- last-block head for this batch ----
    __threadfence();
    if (t == 0)
        sOld = __hip_atomic_fetch_add(&cnt_x3[b], 1, __ATOMIC_ACQ_REL,
                                      __HIP_MEMORY_SCOPE_AGENT);
    __syncthreads();
    if (sOld != 11) return;

    const float* xr = x3w + (size_t)b * 768;
    float a0 = xr[t], a1 = xr[t + 256], a2 = xr[t + 512];
    float mean = bsum256(a0 + a1 + a2, red) * (1.0f / 768.0f);
    float d0 = a0 - mean, d1 = a1 - mean, d2 = a2 - mean;
    float var = bsum256(d0 * d0 + d1 * d1 + d2 * d2, red) * (1.0f / 767.0f);
    float den = sqrtf(var) + 1e-6f;
    ys[t]       = (lnfa[t] * d0) / den + lnfb[t];
    ys[t + 256] = (lnfa[t + 256] * d1) / den + lnfb[t + 256];
    ys[t + 512] = (lnfa[t + 512] * d2) / den + lnfb[t + 512];
    __syncthreads();
    if (t < 100) {
        double a = (double)bpool[t];
        for (int k = 0; k < 768; ++k)
            a = fma((double)ys[k], (double)Wpool[k * 100 + t], a);
        sPd[t] = a;
    } else if (t < 107) {
        int c = t - 100;
        double a = (double)bcls[c];
        for (int k = 0; k < 768; ++k)
            a = fma((double)ys[k], (double)Wcls[k * 7 + c], a);
        sC7d[c] = a;
        out[OUT_CLS_OFF + b * 7 + c] = (float)a;
    }
    __syncthreads();
    double mx = sPd[0];
    for (int j = 1; j < 100; ++j) mx = fmax(mx, sPd[j]);
    double e = (t < 100) ? exp(sPd[t] - mx) : 0.0;
    __syncthreads();
    if (t < 100) sPd[t] = e;
    __syncthreads();
    double zs = 0.0;
    for (int j = 0; j < 100; ++j) zs += sPd[j];
    __syncthreads();
    if (t < 100) sPd[t] = e / zs;
    __syncthreads();
    if (t == 0) {
        double m7 = sC7d[0];
        for (int j = 1; j < 7; ++j) m7 = fmax(m7, sC7d[j]);
        double es[7]; double z = 0.0;
        for (int j = 0; j < 7; ++j) { es[j] = exp(sC7d[j] - m7); z += es[j]; }
        double ent = 0.0;
        for (int j = 0; j < 7; ++j) { double pr = es[j] / z; ent -= pr * log(pr + 1e-9); }
        double ne = ent / log(7.0);
        int kk = (int)floor(1.0 + ne * 99.0);
        kkw[b] = kk < 1 ? 1 : (kk > 100 ? 100 : kk);
    }
    if (t < 100) {
        double pi = sPd[t];
        int r = 0;
        for (int j = 0; j < 100; ++j) {
            double pj = sPd[j];
            r += (pj > pi) || (pj == pi && j < t);
        }
        topw[b * 100 + r] = t;   // descending, stable
    }
}

// ---------------------------------------------------------------------------
// gather: out[b, r, :] = (r < kk[b]) ? pool[top[b][r], :] : 0. grid (100, 8).
__global__ __launch_bounds__(192) void gather_k(
    const float* __restrict__ pool, const int* __restrict__ topw,
    const int* __restrict__ kkw, float* __restrict__ out)
{
    int r = blockIdx.x, b = blockIdx.y, t = threadIdx.x;
    int idx = topw[b * 100 + r];
    bool keep = r < kkw[b];
    const float4* src = (const float4*)(pool + (size_t)idx * 768);
    float4* dst = (float4*)(out + (size_t)b * 76800 + (size_t)r * 768);
    float4 z = {0.f, 0.f, 0.f, 0.f};
    dst[t] = keep ? src[t] : z;
}

// ---------------------------------------------------------------------------
extern "C" void kernel_launch(void* const* d_in, const int* in_sizes, int n_in,
                              void* d_out, int out_size, void* d_ws, size_t ws_size,
                              hipStream_t stream) {
    (void)in_sizes; (void)n_in; (void)out_size; (void)ws_size;
    const float* tf    = (const float*)d_in[0];
    const float* pool  = (const float*)d_in[1];
    const float* clsT  = (const float*)d_in[2];
    const float* Wq    = (const float*)d_in[3];
    const float* bq    = (const float*)d_in[4];
    const float* Wk    = (const float*)d_in[5];
    const float* bk    = (const float*)d_in[6];
    const float* Wv    = (const float*)d_in[7];
    const float* bv    = (const float*)d_in[8];
    const float* Wo    = (const float*)d_in[9];
    const float* bo    = (const float*)d_in[10];
    const float* ln1a  = (const float*)d_in[11];
    const float* ln1b  = (const float*)d_in[12];
    const float* ln2a  = (const float*)d_in[13];
    const float* ln2b  = (const float*)d_in[14];
    const float* W1    = (const float*)d_in[15];
    const float* b1    = (const float*)d_in[16];
    const float* W2    = (const float*)d_in[17];
    const float* b2    = (const float*)d_in[18];
    const float* lnfa  = (const float*)d_in[19];
    const float* lnfb  = (const float*)d_in[20];
    const float* Wpool = (const float*)d_in[21];
    const float* bpool = (const float*)d_in[22];
    const float* Wcls  = (const float*)d_in[23];
    const float* bcls  = (const float*)d_in[24];
    float* out = (float*)d_out;
    char* ws = (char*)d_ws;

    float*  sc    = (float*)(ws + 0);           // 524,288
    float*  qb    = (float*)(ws + 524288);      // 524,288
    float2* stats = (float2*)(ws + 1048576);    // 65,536
    float*  wkqc  = (float*)(ws + 1114112);     // 49,408
    float*  q0    = (float*)(ws + 1163520);     // 3,072
    float*  colw  = (float*)(ws + 1166592);     // 6,144
    float*  c1w   = (float*)(ws + 1172736);     // 512
    int*    cnts  = (int*)(ws + 1173248);       // 64 (cnt_sc[8] | cnt_x3[8])
    float*  up    = (float*)(ws + 1173504);     // 12,582,912
    float*  o0    = (float*)(ws + 13756416);    // 24,576
    float*  x2w   = (float*)(ws + 13780992);    // 24,576
    float*  f1w   = (float*)(ws + 13805568);    // 98,304
    float*  x3w   = (float*)(ws + 13903872);    // 24,576
    int*    topw  = (int*)(ws + 13928448);      // 3,200
    int*    kkw   = (int*)(ws + 13931648);      // 32   (total ~14 MB)
    int*    cnt_sc = cnts;
    int*    cnt_x3 = cnts + 8;

    prep_a<<<24, 256, 0, stream>>>(clsT, ln1a, ln1b, Wq, bq, Wk, q0, colw, cnts);
    prep_b<<<48, 256, 0, stream>>>(Wk, bk, q0, colw, wkqc);
    scores_sm<<<1024, 256, 0, stream>>>(tf, clsT, ln1a, wkqc, sc, stats, qb, c1w, cnt_sc);
    upart_k<<<256, 256, 0, stream>>>(tf, clsT, qb, up);
    o0_k<<<dim3(16, 8), 256, 0, stream>>>(up, c1w, ln1a, ln1b, Wv, bv, o0);
    x2_k<<<dim3(12, 8), 256, 0, stream>>>(o0, Wo, bo, clsT, x2w);
    f1_k<<<dim3(24, 8), 256, 0, stream>>>(x2w, ln2a, ln2b, W1, b1, f1w);
    x3ld_k<<<dim3(12, 8), 256, 0, stream>>>(f1w, W2, b2, x2w, x3w, lnfa, lnfb,
                                            Wpool, Wcls, bpool, bcls, out,
                                            topw, kkw, cnt_x3);
    gather_k<<<dim3(100, 8), 192, 0, stream>>>(pool, topw, kkw, out);
}

// Round 9
// 145.720 us; speedup vs baseline: 2.5050x; 1.7943x over previous
//
#include <hip/hip_runtime.h>

// ---------------------------------------------------------------------------
// PromptSelector — collapsed algebra, 10 launches.
//   scores[b,h,j] = rden_j*(dot(ga*x_j, wk[:,h]) - mean_j*Sgw[h]) + CgbC[h]
//   u[b,h,:] = ga ⊙ (Σ_j q_j x_j − c1) + gb,   q_j = p_j·rden_j, c1 = Σ q_j·mean_j
// Round 9: round-8's fused softmax tail made ln_scores' wk registers spill
// (VGPR 88 -> 48, 41 -> 148 µs). Reverted ln_scores to round-6 body verbatim;
// softmax+q-emit is a standalone 128-block kernel. Keep x3ld_k fused head.
// ---------------------------------------------------------------------------

#define OUT_CLS_OFF 614400   // 8*100*768

__device__ __forceinline__ float bsum256(float v, float* red) {
    int lane = threadIdx.x & 63, w = threadIdx.x >> 6;
#pragma unroll
    for (int off = 1; off < 64; off <<= 1) v += __shfl_xor(v, off);
    __syncthreads();
    if (lane == 0) red[w] = v;
    __syncthreads();
    return red[0] + red[1] + red[2] + red[3];
}
__device__ __forceinline__ float bmax256(float v, float* red) {
    int lane = threadIdx.x & 63, w = threadIdx.x >> 6;
#pragma unroll
    for (int off = 1; off < 64; off <<= 1) v = fmaxf(v, __shfl_xor(v, off));
    __syncthreads();
    if (lane == 0) red[w] = v;
    __syncthreads();
    return fmaxf(fmaxf(red[0], red[1]), fmaxf(red[2], red[3]));
}

// ---------------------------------------------------------------------------
// prep_a: blocks 0-11 -> q0 = LN1(cls) @ Wq + bq; blocks 12-23 -> colga/colgb
// (ga/gb-weighted column sums of Wk). Block 0 also zeroes the phase counters.
__global__ __launch_bounds__(256) void prep_a(
    const float* __restrict__ clsT, const float* __restrict__ ga,
    const float* __restrict__ gb, const float* __restrict__ Wq,
    const float* __restrict__ bq, const float* __restrict__ Wk,
    float* __restrict__ q0, float* __restrict__ colw, int* __restrict__ cnts)
{
    __shared__ float ys[768];
    __shared__ float red[4];
    __shared__ float4 partA[16][17];
    __shared__ float4 partB[16][17];
    int t = threadIdx.x;
    if (blockIdx.x == 0 && t < 16) cnts[t] = 0;
    if (blockIdx.x < 12) {
        float a0 = clsT[t], a1 = clsT[t + 256], a2 = clsT[t + 512];
        float mean = bsum256(a0 + a1 + a2, red) * (1.0f / 768.0f);
        float d0 = a0 - mean, d1 = a1 - mean, d2 = a2 - mean;
        float var = bsum256(d0 * d0 + d1 * d1 + d2 * d2, red) * (1.0f / 767.0f);
        float den = sqrtf(var) + 1e-6f;
        ys[t]       = (ga[t] * d0) / den + gb[t];
        ys[t + 256] = (ga[t + 256] * d1) / den + gb[t + 256];
        ys[t + 512] = (ga[t + 512] * d2) / den + gb[t + 512];
        __syncthreads();
        int c = blockIdx.x * 64 + (t & 15) * 4;
        int kq = t >> 4;
        float4 acc = {0.f, 0.f, 0.f, 0.f};
#pragma unroll 8
        for (int i = 0; i < 48; ++i) {
            int k = kq * 48 + i;
            float4 w = *(const float4*)&Wq[(size_t)k * 768 + c];
            float y = ys[k];
            acc.x = fmaf(y, w.x, acc.x); acc.y = fmaf(y, w.y, acc.y);
            acc.z = fmaf(y, w.z, acc.z); acc.w = fmaf(y, w.w, acc.w);
        }
        partA[kq][t & 15] = acc;
        __syncthreads();
        if (t < 16) {
            float4 s = {0.f, 0.f, 0.f, 0.f};
#pragma unroll
            for (int i = 0; i < 16; ++i) {
                float4 v = partA[i][t];
                s.x += v.x; s.y += v.y; s.z += v.z; s.w += v.w;
            }
            int cc = blockIdx.x * 64 + t * 4;
            float4 b4 = *(const float4*)&bq[cc];
            q0[cc] = s.x + b4.x; q0[cc + 1] = s.y + b4.y;
            q0[cc + 2] = s.z + b4.z; q0[cc + 3] = s.w + b4.w;
        }
    } else {
        int c = (blockIdx.x - 12) * 64 + (t & 15) * 4;
        int kq = t >> 4;
        float4 aa = {0.f, 0.f, 0.f, 0.f}, ab = {0.f, 0.f, 0.f, 0.f};
#pragma unroll 8
        for (int i = 0; i < 48; ++i) {
            int k = kq * 48 + i;
            float4 w = *(const float4*)&Wk[(size_t)k * 768 + c];
            float g = ga[k], h = gb[k];
            aa.x = fmaf(g, w.x, aa.x); aa.y = fmaf(g, w.y, aa.y);
            aa.z = fmaf(g, w.z, aa.z); aa.w = fmaf(g, w.w, aa.w);
            ab.x = fmaf(h, w.x, ab.x); ab.y = fmaf(h, w.y, ab.y);
            ab.z = fmaf(h, w.z, ab.z); ab.w = fmaf(h, w.w, ab.w);
        }
        partA[kq][t & 15] = aa;
        partB[kq][t & 15] = ab;
        __syncthreads();
        if (t < 16) {
            float4 sa = {0.f, 0.f, 0.f, 0.f}, sb = {0.f, 0.f, 0.f, 0.f};
#pragma unroll
            for (int i = 0; i < 16; ++i) {
                float4 va = partA[i][t], vb = partB[i][t];
                sa.x += va.x; sa.y += va.y; sa.z += va.z; sa.w += va.w;
                sb.x += vb.x; sb.y += vb.y; sb.z += vb.z; sb.w += vb.w;
            }
            int cc = (blockIdx.x - 12) * 64 + t * 4;
            *(float4*)&colw[cc] = sa;
            *(float4*)&colw[768 + cc] = sb;
        }
    }
}

// ---------------------------------------------------------------------------
// prep_b: wkq[k][h] = (Wk[k,h48..] . q0_h)/sqrt(48); block 0 also computes
// Sgw[h] (at 12304) and CgbC[h] (at 12320) from colga/colgb + bk.
__global__ __launch_bounds__(256) void prep_b(
    const float* __restrict__ Wk, const float* __restrict__ bk,
    const float* __restrict__ q0, const float* __restrict__ colw,
    float* __restrict__ wkqc)
{
    __shared__ float qs[768];
    int t = threadIdx.x;
    qs[t] = q0[t]; qs[t + 256] = q0[t + 256]; qs[t + 512] = q0[t + 512];
    __syncthreads();
    const float invs = 0.14433756729740643f;  // 1/sqrt(48)
    int kl = t >> 4, h = t & 15;
    int k = blockIdx.x * 16 + kl;
    const float* wr = Wk + (size_t)k * 768 + h * 48;
    const float* qh = qs + h * 48;
    float a = 0.f;
#pragma unroll
    for (int d = 0; d < 48; d += 4) {
        float4 w = *(const float4*)&wr[d];
        a += w.x * qh[d] + w.y * qh[d + 1] + w.z * qh[d + 2] + w.w * qh[d + 3];
    }
    wkqc[k * 16 + h] = a * invs;
    if (blockIdx.x == 0 && t < 16) {
        float cd = 0.f, sa = 0.f, sb = 0.f;
        for (int d = 0; d < 48; ++d) {
            int dd = t * 48 + d;
            cd = fmaf(bk[dd], qs[dd], cd);
            sa = fmaf(colw[dd], qs[dd], sa);
            sb = fmaf(colw[768 + dd], qs[dd], sb);
        }
        wkqc[12304 + t] = sa * invs;
        wkqc[12320 + t] = sb * invs + cd * invs;
    }
}

// ---------------------------------------------------------------------------
// Pass 1: scores for all 8192 rows via raw moments + register-held wk.
// grid 1024 (8 rows/block). Per row: 2 barriers. EXACT round-6 body (no tail
// code: keeping it register-clean avoids the round-8 wk spill, VGPR 88 not 48).
__global__ __launch_bounds__(256) void ln_scores(
    const float* __restrict__ tf, const float* __restrict__ clsT,
    const float* __restrict__ ga, const float* __restrict__ wkqc,
    float* __restrict__ sc, float2* __restrict__ stats)
{
    __shared__ float tr[256][17];      // padded transpose buffer (17.4 KB)
    __shared__ float partw[4][16];
    __shared__ float red[2][4][2];     // s1,s2 per wave, row-parity dbuf
    int t = threadIdx.x;
    int l = t & 63, w = t >> 6;

    // 48 wk registers: rows t, t+256, t+512 (16 heads each)
    float wk0[16], wk1[16], wk2[16];
    {
        const float4* p0 = (const float4*)(wkqc + t * 16);
        const float4* p1 = (const float4*)(wkqc + (t + 256) * 16);
        const float4* p2 = (const float4*)(wkqc + (t + 512) * 16);
#pragma unroll
        for (int q = 0; q < 4; ++q) {
            float4 v0 = p0[q], v1 = p1[q], v2 = p2[q];
            wk0[q * 4] = v0.x; wk0[q * 4 + 1] = v0.y; wk0[q * 4 + 2] = v0.z; wk0[q * 4 + 3] = v0.w;
            wk1[q * 4] = v1.x; wk1[q * 4 + 1] = v1.y; wk1[q * 4 + 2] = v1.z; wk1[q * 4 + 3] = v1.w;
            wk2[q * 4] = v2.x; wk2[q * 4 + 1] = v2.y; wk2[q * 4 + 2] = v2.z; wk2[q * 4 + 3] = v2.w;
        }
    }
    float ga0 = ga[t], ga1 = ga[t + 256], ga2 = ga[t + 512];
    float Sg = wkqc[12304 + (t & 15)];
    float Cg = wkqc[12320 + (t & 15)];

    int r0 = blockIdx.x * 8;
    for (int r = 0; r < 8; ++r) {
        int row = r0 + r;
        int b = row >> 10, j = row & 1023;
        const float* src = j ? (tf + ((size_t)b * 1023 + (j - 1)) * 768) : clsT;
        float x0 = src[t], x1 = src[t + 256], x2 = src[t + 512];
        float s1 = x0 + x1 + x2;
        float s2 = fmaf(x0, x0, fmaf(x1, x1, x2 * x2));
        float g0 = ga0 * x0, g1 = ga1 * x1, g2 = ga2 * x2;
        float dt[16];
#pragma unroll
        for (int h = 0; h < 16; ++h)
            dt[h] = fmaf(g0, wk0[h], fmaf(g1, wk1[h], g2 * wk2[h]));
        // wave butterfly for raw moments
#pragma unroll
        for (int off = 1; off < 64; off <<= 1) {
            s1 += __shfl_xor(s1, off);
            s2 += __shfl_xor(s2, off);
        }
        if (l == 0) { red[r & 1][w][0] = s1; red[r & 1][w][1] = s2; }
#pragma unroll
        for (int h = 0; h < 16; ++h) tr[t][h] = dt[h];
        __syncthreads();                       // B1
        int hh = t & 15, ch = t >> 4;
        float v = 0.f;
#pragma unroll
        for (int i = 0; i < 16; ++i) v += tr[ch * 16 + i][hh];
        v += __shfl_xor(v, 16);
        v += __shfl_xor(v, 32);
        if (l < 16) partw[w][l] = v;
        __syncthreads();                       // B2
        if (t < 16) {
            float dtot = partw[0][t] + partw[1][t] + partw[2][t] + partw[3][t];
            float s1t = red[r & 1][0][0] + red[r & 1][1][0] + red[r & 1][2][0] + red[r & 1][3][0];
            float s2t = red[r & 1][0][1] + red[r & 1][1][1] + red[r & 1][2][1] + red[r & 1][3][1];
            float mean = s1t * (1.0f / 768.0f);
            float var = (s2t - mean * s1t) * (1.0f / 767.0f);
            float rden = 1.0f / (sqrtf(var) + 1e-6f);
            float sv = rden * (dtot - mean * Sg) + Cg;
            sc[(((size_t)b * 16 + t) << 10) + j] = sv;
            if (t == 0) stats[row] = make_float2(mean, rden);
        }
    }
}

// ---------------------------------------------------------------------------
// softmax over j (1024) per (b,h), emitting q = p*rden and c1 = sum q*mean.
// grid 128.
__global__ __launch_bounds__(256) void softmax_q(
    const float* __restrict__ sc, const float2* __restrict__ stats,
    float* __restrict__ qb, float* __restrict__ c1w)
{
    __shared__ float red[4];
    int bh = blockIdx.x, t = threadIdx.x;
    int b = bh >> 4;
    const float4* s4 = (const float4*)(sc + ((size_t)bh << 10));
    float4 v = s4[t];
    float m = fmaxf(fmaxf(v.x, v.y), fmaxf(v.z, v.w));
    float M = bmax256(m, red);
    float e0 = expf(v.x - M), e1 = expf(v.y - M), e2 = expf(v.z - M), e3 = expf(v.w - M);
    float Z = bsum256(e0 + e1 + e2 + e3, red);
    float2 st0 = stats[(b << 10) + 4 * t];
    float2 st1 = stats[(b << 10) + 4 * t + 1];
    float2 st2 = stats[(b << 10) + 4 * t + 2];
    float2 st3 = stats[(b << 10) + 4 * t + 3];
    float q0v = (e0 / Z) * st0.y, q1v = (e1 / Z) * st1.y;
    float q2v = (e2 / Z) * st2.y, q3v = (e3 / Z) * st3.y;
    float c1t = bsum256(q0v * st0.x + q1v * st1.x + q2v * st2.x + q3v * st3.x, red);
    float4 o4; o4.x = q0v; o4.y = q1v; o4.z = q2v; o4.w = q3v;
    ((float4*)(qb + ((size_t)bh << 10)))[t] = o4;
    if (t == 0) c1w[bh] = c1t;
}

// ---------------------------------------------------------------------------
// wsum partials: up[b][jc][h][:] = Σ_j qb*x over 32-row chunk. grid 256.
__global__ __launch_bounds__(256) void upart_k(
    const float* __restrict__ tf, const float* __restrict__ clsT,
    const float* __restrict__ qb, float* __restrict__ up)
{
    __shared__ float qs_s[16][32];
    int b = blockIdx.x & 7, jc = blockIdx.x >> 3;
    int t = threadIdx.x;
    if (t < 128) {
        int h = t >> 3, j4 = (t & 7) * 4;
        float4 pv = *(const float4*)(qb + (((size_t)b * 16 + h) << 10) + jc * 32 + j4);
        qs_s[h][j4] = pv.x; qs_s[h][j4 + 1] = pv.y;
        qs_s[h][j4 + 2] = pv.z; qs_s[h][j4 + 3] = pv.w;
    }
    __syncthreads();
    float acc[16][3];
#pragma unroll
    for (int h = 0; h < 16; ++h) { acc[h][0] = 0.f; acc[h][1] = 0.f; acc[h][2] = 0.f; }
    int j0 = jc * 32;
    const float* sp0 = j0 ? (tf + ((size_t)b * 1023 + (j0 - 1)) * 768) : clsT;
    float nx0 = sp0[t], nx1 = sp0[t + 256], nx2 = sp0[t + 512];
    for (int jj = 0; jj < 32; ++jj) {
        float x0 = nx0, x1 = nx1, x2 = nx2;
        if (jj < 31) {
            const float* sp = tf + ((size_t)b * 1023 + j0 + jj) * 768;
            nx0 = sp[t]; nx1 = sp[t + 256]; nx2 = sp[t + 512];
        }
#pragma unroll
        for (int h = 0; h < 16; ++h) {
            float qh = qs_s[h][jj];
            acc[h][0] = fmaf(qh, x0, acc[h][0]);
            acc[h][1] = fmaf(qh, x1, acc[h][1]);
            acc[h][2] = fmaf(qh, x2, acc[h][2]);
        }
    }
    float* o = up + (((size_t)b * 32 + jc) * 16) * 768;
#pragma unroll
    for (int h = 0; h < 16; ++h) {
        o[h * 768 + t] = acc[h][0];
        o[h * 768 + t + 256] = acc[h][1];
        o[h * 768 + t + 512] = acc[h][2];
    }
}

// ---------------------------------------------------------------------------
// o0 = (ga⊙(wsum−c1)+gb) @ Wv_h + bv. grid (16 h, 8 b).
__global__ __launch_bounds__(256) void o0_k(
    const float* __restrict__ up, const float* __restrict__ c1w,
    const float* __restrict__ ga, const float* __restrict__ gb,
    const float* __restrict__ Wv, const float* __restrict__ bv,
    float* __restrict__ o0)
{
    __shared__ float us[768];
    __shared__ float part[4][64];
    int h = blockIdx.x, b = blockIdx.y, t = threadIdx.x;
    float s0 = 0.f, s1 = 0.f, s2 = 0.f;
#pragma unroll 8
    for (int jc = 0; jc < 32; ++jc) {
        const float* q = up + (((size_t)b * 32 + jc) * 16 + h) * 768;
        s0 += q[t]; s1 += q[t + 256]; s2 += q[t + 512];
    }
    float c1 = c1w[b * 16 + h];
    us[t]       = ga[t] * (s0 - c1) + gb[t];
    us[t + 256] = ga[t + 256] * (s1 - c1) + gb[t + 256];
    us[t + 512] = ga[t + 512] * (s2 - c1) + gb[t + 512];
    __syncthreads();
    int dd = t & 63, kg = t >> 6;
    float a = 0.f;
    if (dd < 48) {
#pragma unroll 8
        for (int i = 0; i < 192; ++i) {
            int k = kg * 192 + i;
            a = fmaf(us[k], Wv[(size_t)k * 768 + h * 48 + dd], a);
        }
    }
    part[kg][dd] = a;
    __syncthreads();
    if (t < 48)
        o0[(size_t)b * 768 + h * 48 + t] =
            part[0][t] + part[1][t] + part[2][t] + part[3][t] + bv[h * 48 + t];
}

// ---------------------------------------------------------------------------
// x2 = clsT + o0 @ Wo + bo. grid (12, 8).
__global__ __launch_bounds__(256) void x2_k(
    const float* __restrict__ o0, const float* __restrict__ Wo,
    const float* __restrict__ bo, const float* __restrict__ clsT,
    float* __restrict__ x2w)
{
    __shared__ float ys[768];
    __shared__ float4 part[16][17];
    int b = blockIdx.y, t = threadIdx.x;
    const float* xr = o0 + (size_t)b * 768;
    ys[t] = xr[t]; ys[t + 256] = xr[t + 256]; ys[t + 512] = xr[t + 512];
    __syncthreads();
    int c = blockIdx.x * 64 + (t & 15) * 4;
    int kq = t >> 4;
    float4 acc = {0.f, 0.f, 0.f, 0.f};
#pragma unroll 8
    for (int i = 0; i < 48; ++i) {
        int k = kq * 48 + i;
        float4 w = *(const float4*)&Wo[(size_t)k * 768 + c];
        float y = ys[k];
        acc.x = fmaf(y, w.x, acc.x); acc.y = fmaf(y, w.y, acc.y);
        acc.z = fmaf(y, w.z, acc.z); acc.w = fmaf(y, w.w, acc.w);
    }
    part[kq][t & 15] = acc;
    __syncthreads();
    if (t < 16) {
        float4 s = {0.f, 0.f, 0.f, 0.f};
#pragma unroll
        for (int i = 0; i < 16; ++i) {
            float4 v = part[i][t];
            s.x += v.x; s.y += v.y; s.z += v.z; s.w += v.w;
        }
        int cc = blockIdx.x * 64 + t * 4;
        float4 b4 = *(const float4*)&bo[cc];
        float4 r4 = *(const float4*)&clsT[cc];
        float* o = x2w + (size_t)b * 768 + cc;
        o[0] = s.x + b4.x + r4.x; o[1] = s.y + b4.y + r4.y;
        o[2] = s.z + b4.z + r4.z; o[3] = s.w + b4.w + r4.w;
    }
}

// ---------------------------------------------------------------------------
// f1 = relu(LN2(x2) @ W1 + b1), LN fused. grid (24, 8).
__global__ __launch_bounds__(256) void f1_k(
    const float* __restrict__ x2w, const float* __restrict__ ga,
    const float* __restrict__ gb, const float* __restrict__ W1,
    const float* __restrict__ b1, float* __restrict__ f1w)
{
    __shared__ float ys[768];
    __shared__ float red[4];
    __shared__ float4 part[8][33];
    int b = blockIdx.y, t = threadIdx.x;
    const float* xr = x2w + (size_t)b * 768;
    float a0 = xr[t], a1 = xr[t + 256], a2 = xr[t + 512];
    float mean = bsum256(a0 + a1 + a2, red) * (1.0f / 768.0f);
    float d0 = a0 - mean, d1 = a1 - mean, d2 = a2 - mean;
    float var = bsum256(d0 * d0 + d1 * d1 + d2 * d2, red) * (1.0f / 767.0f);
    float den = sqrtf(var) + 1e-6f;
    ys[t]       = (ga[t] * d0) / den + gb[t];
    ys[t + 256] = (ga[t + 256] * d1) / den + gb[t + 256];
    ys[t + 512] = (ga[t + 512] * d2) / den + gb[t + 512];
    __syncthreads();
    int c = blockIdx.x * 128 + (t & 31) * 4;
    int kq = t >> 5;
    float4 acc = {0.f, 0.f, 0.f, 0.f};
#pragma unroll 8
    for (int i = 0; i < 96; ++i) {
        int k = kq * 96 + i;
        float4 w = *(const float4*)&W1[(size_t)k * 3072 + c];
        float y = ys[k];
        acc.x = fmaf(y, w.x, acc.x); acc.y = fmaf(y, w.y, acc.y);
        acc.z = fmaf(y, w.z, acc.z); acc.w = fmaf(y, w.w, acc.w);
    }
    part[kq][t & 31] = acc;
    __syncthreads();
    if (t < 32) {
        float4 s = {0.f, 0.f, 0.f, 0.f};
#pragma unroll
        for (int i = 0; i < 8; ++i) {
            float4 v = part[i][t];
            s.x += v.x; s.y += v.y; s.z += v.z; s.w += v.w;
        }
        int cc = blockIdx.x * 128 + t * 4;
        float4 b4 = *(const float4*)&b1[cc];
        float* o = f1w + (size_t)b * 3072 + cc;
        o[0] = fmaxf(s.x + b4.x, 0.f); o[1] = fmaxf(s.y + b4.y, 0.f);
        o[2] = fmaxf(s.z + b4.z, 0.f); o[3] = fmaxf(s.w + b4.w, 0.f);
    }
}

// ---------------------------------------------------------------------------
// x3 = x2 + f1 @ W2 + b2 with fused head: last block per batch does
// LNf + double-precision pool/class logits + entropy + rank. grid (12, 8).
__global__ __launch_bounds__(256) void x3ld_k(
    const float* __restrict__ f1w, const float* __restrict__ W2,
    const float* __restrict__ b2, const float* __restrict__ x2w,
    float* __restrict__ x3w, const float* __restrict__ lnfa,
    const float* __restrict__ lnfb, const float* __restrict__ Wpool,
    const float* __restrict__ Wcls, const float* __restrict__ bpool,
    const float* __restrict__ bcls, float* __restrict__ out,
    int* __restrict__ topw, int* __restrict__ kkw, int* __restrict__ cnt_x3)
{
    __shared__ float ys[3072];
    __shared__ float red[4];
    __shared__ float4 part[16][17];
    __shared__ double sPd[100];
    __shared__ double sC7d[7];
    __shared__ int sOld;
    int b = blockIdx.y, t = threadIdx.x;
    {
        const float* xr = f1w + (size_t)b * 3072;
        for (int i = t; i < 3072; i += 256) ys[i] = xr[i];
        __syncthreads();
        int c = blockIdx.x * 64 + (t & 15) * 4;
        int kq = t >> 4;
        float4 acc = {0.f, 0.f, 0.f, 0.f};
#pragma unroll 8
        for (int i = 0; i < 192; ++i) {
            int k = kq * 192 + i;
            float4 w = *(const float4*)&W2[(size_t)k * 768 + c];
            float y = ys[k];
            acc.x = fmaf(y, w.x, acc.x); acc.y = fmaf(y, w.y, acc.y);
            acc.z = fmaf(y, w.z, acc.z); acc.w = fmaf(y, w.w, acc.w);
        }
        part[kq][t & 15] = acc;
        __syncthreads();
        if (t < 16) {
            float4 s = {0.f, 0.f, 0.f, 0.f};
#pragma unroll
            for (int i = 0; i < 16; ++i) {
                float4 v = part[i][t];
                s.x += v.x; s.y += v.y; s.z += v.z; s.w += v.w;
            }
            int cc = blockIdx.x * 64 + t * 4;
            float4 b4 = *(const float4*)&b2[cc];
            const float* x2r = x2w + (size_t)b * 768 + cc;
            float* o = x3w + (size_t)b * 768 + cc;
            o[0] = x2r[0] + s.x + b4.x; o[1] = x2r[1] + s.y + b4.y;
            o[2] = x2r[2] + s.z + b4.z; o[3] = x2r[3] + s.w + b4.w;
        }
    }
    // ---- last-block head for this batch ----
    __threadfence();
    if (t == 0)
        sOld = __hip_atomic_fetch_add(&cnt_x3[b], 1, __ATOMIC_ACQ_REL,
                                      __HIP_MEMORY_SCOPE_AGENT);
    __syncthreads();
    if (sOld != 11) return;

    const float* xr = x3w + (size_t)b * 768;
    float a0 = xr[t], a1 = xr[t + 256], a2 = xr[t + 512];
    float mean = bsum256(a0 + a1 + a2, red) * (1.0f / 768.0f);
    float d0 = a0 - mean, d1 = a1 - mean, d2 = a2 - mean;
    float var = bsum256(d0 * d0 + d1 * d1 + d2 * d2, red) * (1.0f / 767.0f);
    float den = sqrtf(var) + 1e-6f;
    ys[t]       = (lnfa[t] * d0) / den + lnfb[t];
    ys[t + 256] = (lnfa[t + 256] * d1) / den + lnfb[t + 256];
    ys[t + 512] = (lnfa[t + 512] * d2) / den + lnfb[t + 512];
    __syncthreads();
    if (t < 100) {
        double a = (double)bpool[t];
        for (int k = 0; k < 768; ++k)
            a = fma((double)ys[k], (double)Wpool[k * 100 + t], a);
        sPd[t] = a;
    } else if (t < 107) {
        int c = t - 100;
        double a = (double)bcls[c];
        for (int k = 0; k < 768; ++k)
            a = fma((double)ys[k], (double)Wcls[k * 7 + c], a);
        sC7d[c] = a;
        out[OUT_CLS_OFF + b * 7 + c] = (float)a;
    }
    __syncthreads();
    double mx = sPd[0];
    for (int j = 1; j < 100; ++j) mx = fmax(mx, sPd[j]);
    double e = (t < 100) ? exp(sPd[t] - mx) : 0.0;
    __syncthreads();
    if (t < 100) sPd[t] = e;
    __syncthreads();
    double zs = 0.0;
    for (int j = 0; j < 100; ++j) zs += sPd[j];
    __syncthreads();
    if (t < 100) sPd[t] = e / zs;
    __syncthreads();
    if (t == 0) {
        double m7 = sC7d[0];
        for (int j = 1; j < 7; ++j) m7 = fmax(m7, sC7d[j]);
        double es[7]; double z = 0.0;
        for (int j = 0; j < 7; ++j) { es[j] = exp(sC7d[j] - m7); z += es[j]; }
        double ent = 0.0;
        for (int j = 0; j < 7; ++j) { double pr = es[j] / z; ent -= pr * log(pr + 1e-9); }
        double ne = ent / log(7.0);
        int kk = (int)floor(1.0 + ne * 99.0);
        kkw[b] = kk < 1 ? 1 : (kk > 100 ? 100 : kk);
    }
    if (t < 100) {
        double pi = sPd[t];
        int r = 0;
        for (int j = 0; j < 100; ++j) {
            double pj = sPd[j];
            r += (pj > pi) || (pj == pi && j < t);
        }
        topw[b * 100 + r] = t;   // descending, stable
    }
}

// ---------------------------------------------------------------------------
// gather: out[b, r, :] = (r < kk[b]) ? pool[top[b][r], :] : 0. grid (100, 8).
__global__ __launch_bounds__(192) void gather_k(
    const float* __restrict__ pool, const int* __restrict__ topw,
    const int* __restrict__ kkw, float* __restrict__ out)
{
    int r = blockIdx.x, b = blockIdx.y, t = threadIdx.x;
    int idx = topw[b * 100 + r];
    bool keep = r < kkw[b];
    const float4* src = (const float4*)(pool + (size_t)idx * 768);
    float4* dst = (float4*)(out + (size_t)b * 76800 + (size_t)r * 768);
    float4 z = {0.f, 0.f, 0.f, 0.f};
    dst[t] = keep ? src[t] : z;
}

// ---------------------------------------------------------------------------
extern "C" void kernel_launch(void* const* d_in, const int* in_sizes, int n_in,
                              void* d_out, int out_size, void* d_ws, size_t ws_size,
                              hipStream_t stream) {
    (void)in_sizes; (void)n_in; (void)out_size; (void)ws_size;
    const float* tf    = (const float*)d_in[0];
    const float* pool  = (const float*)d_in[1];
    const float* clsT  = (const float*)d_in[2];
    const float* Wq    = (const float*)d_in[3];
    const float* bq    = (const float*)d_in[4];
    const float* Wk    = (const float*)d_in[5];
    const float* bk    = (const float*)d_in[6];
    const float* Wv    = (const float*)d_in[7];
    const float* bv    = (const float*)d_in[8];
    const float* Wo    = (const float*)d_in[9];
    const float* bo    = (const float*)d_in[10];
    const float* ln1a  = (const float*)d_in[11];
    const float* ln1b  = (const float*)d_in[12];
    const float* ln2a  = (const float*)d_in[13];
    const float* ln2b  = (const float*)d_in[14];
    const float* W1    = (const float*)d_in[15];
    const float* b1    = (const float*)d_in[16];
    const float* W2    = (const float*)d_in[17];
    const float* b2    = (const float*)d_in[18];
    const float* lnfa  = (const float*)d_in[19];
    const float* lnfb  = (const float*)d_in[20];
    const float* Wpool = (const float*)d_in[21];
    const float* bpool = (const float*)d_in[22];
    const float* Wcls  = (const float*)d_in[23];
    const float* bcls  = (const float*)d_in[24];
    float* out = (float*)d_out;
    char* ws = (char*)d_ws;

    float*  sc    = (float*)(ws + 0);           // 524,288
    float*  qb    = (float*)(ws + 524288);      // 524,288
    float2* stats = (float2*)(ws + 1048576);    // 65,536
    float*  wkqc  = (float*)(ws + 1114112);     // 49,408
    float*  q0    = (float*)(ws + 1163520);     // 3,072
    float*  colw  = (float*)(ws + 1166592);     // 6,144
    float*  c1w   = (float*)(ws + 1172736);     // 512
    int*    cnts  = (int*)(ws + 1173248);       // 64
    float*  up    = (float*)(ws + 1173504);     // 12,582,912
    float*  o0    = (float*)(ws + 13756416);    // 24,576
    float*  x2w   = (float*)(ws + 13780992);    // 24,576
    float*  f1w   = (float*)(ws + 13805568);    // 98,304
    float*  x3w   = (float*)(ws + 13903872);    // 24,576
    int*    topw  = (int*)(ws + 13928448);      // 3,200
    int*    kkw   = (int*)(ws + 13931648);      // 32   (total ~14 MB)
    int*    cnt_x3 = cnts + 8;

    prep_a<<<24, 256, 0, stream>>>(clsT, ln1a, ln1b, Wq, bq, Wk, q0, colw, cnts);
    prep_b<<<48, 256, 0, stream>>>(Wk, bk, q0, colw, wkqc);
    ln_scores<<<1024, 256, 0, stream>>>(tf, clsT, ln1a, wkqc, sc, stats);
    softmax_q<<<128, 256, 0, stream>>>(sc, stats, qb, c1w);
    upart_k<<<256, 256, 0, stream>>>(tf, clsT, qb, up);
    o0_k<<<dim3(16, 8), 256, 0, stream>>>(up, c1w, ln1a, ln1b, Wv, bv, o0);
    x2_k<<<dim3(12, 8), 256, 0, stream>>>(o0, Wo, bo, clsT, x2w);
    f1_k<<<dim3(24, 8), 256, 0, stream>>>(x2w, ln2a, ln2b, W1, b1, f1w);
    x3ld_k<<<dim3(12, 8), 256, 0, stream>>>(f1w, W2, b2, x2w, x3w, lnfa, lnfb,
                                            Wpool, Wcls, bpool, bcls, out,
                                            topw, kkw, cnt_x3);
    gather_k<<<dim3(100, 8), 192, 0, stream>>>(pool, topw, kkw, out);
}

// Round 10
// 107.082 us; speedup vs baseline: 3.4088x; 1.3608x over previous
//
#include <hip/hip_runtime.h>

// ---------------------------------------------------------------------------
// PromptSelector — collapsed algebra, 12 launches.
//   scores[b,h,j] = rden_j*(dot(ga*x_j, wk[:,h]) - mean_j*Sgw[h]) + CgbC[h]
//   u[b,h,:] = ga ⊙ (Σ_j q_j x_j − c1) + gb,   q_j = p_j·rden_j, c1 = Σ q_j·mean_j
// Round 10: round-9's x3ld_k fused head was a 100 µs latency trap (8 blocks x
// 768 serial double FMAs). Head restored to the proven k-split logits_part
// (grid 8x8) + head_decide (grid 8). x3_k back to tail-free round-6 form.
// ---------------------------------------------------------------------------

#define OUT_CLS_OFF 614400   // 8*100*768

__device__ __forceinline__ float bsum256(float v, float* red) {
    int lane = threadIdx.x & 63, w = threadIdx.x >> 6;
#pragma unroll
    for (int off = 1; off < 64; off <<= 1) v += __shfl_xor(v, off);
    __syncthreads();
    if (lane == 0) red[w] = v;
    __syncthreads();
    return red[0] + red[1] + red[2] + red[3];
}
__device__ __forceinline__ float bmax256(float v, float* red) {
    int lane = threadIdx.x & 63, w = threadIdx.x >> 6;
#pragma unroll
    for (int off = 1; off < 64; off <<= 1) v = fmaxf(v, __shfl_xor(v, off));
    __syncthreads();
    if (lane == 0) red[w] = v;
    __syncthreads();
    return fmaxf(fmaxf(red[0], red[1]), fmaxf(red[2], red[3]));
}

// ---------------------------------------------------------------------------
// prep_a: blocks 0-11 -> q0 = LN1(cls) @ Wq + bq; blocks 12-23 -> colga/colgb
// (ga/gb-weighted column sums of Wk).
__global__ __launch_bounds__(256) void prep_a(
    const float* __restrict__ clsT, const float* __restrict__ ga,
    const float* __restrict__ gb, const float* __restrict__ Wq,
    const float* __restrict__ bq, const float* __restrict__ Wk,
    float* __restrict__ q0, float* __restrict__ colw)
{
    __shared__ float ys[768];
    __shared__ float red[4];
    __shared__ float4 partA[16][17];
    __shared__ float4 partB[16][17];
    int t = threadIdx.x;
    if (blockIdx.x < 12) {
        float a0 = clsT[t], a1 = clsT[t + 256], a2 = clsT[t + 512];
        float mean = bsum256(a0 + a1 + a2, red) * (1.0f / 768.0f);
        float d0 = a0 - mean, d1 = a1 - mean, d2 = a2 - mean;
        float var = bsum256(d0 * d0 + d1 * d1 + d2 * d2, red) * (1.0f / 767.0f);
        float den = sqrtf(var) + 1e-6f;
        ys[t]       = (ga[t] * d0) / den + gb[t];
        ys[t + 256] = (ga[t + 256] * d1) / den + gb[t + 256];
        ys[t + 512] = (ga[t + 512] * d2) / den + gb[t + 512];
        __syncthreads();
        int c = blockIdx.x * 64 + (t & 15) * 4;
        int kq = t >> 4;
        float4 acc = {0.f, 0.f, 0.f, 0.f};
#pragma unroll 8
        for (int i = 0; i < 48; ++i) {
            int k = kq * 48 + i;
            float4 w = *(const float4*)&Wq[(size_t)k * 768 + c];
            float y = ys[k];
            acc.x = fmaf(y, w.x, acc.x); acc.y = fmaf(y, w.y, acc.y);
            acc.z = fmaf(y, w.z, acc.z); acc.w = fmaf(y, w.w, acc.w);
        }
        partA[kq][t & 15] = acc;
        __syncthreads();
        if (t < 16) {
            float4 s = {0.f, 0.f, 0.f, 0.f};
#pragma unroll
            for (int i = 0; i < 16; ++i) {
                float4 v = partA[i][t];
                s.x += v.x; s.y += v.y; s.z += v.z; s.w += v.w;
            }
            int cc = blockIdx.x * 64 + t * 4;
            float4 b4 = *(const float4*)&bq[cc];
            q0[cc] = s.x + b4.x; q0[cc + 1] = s.y + b4.y;
            q0[cc + 2] = s.z + b4.z; q0[cc + 3] = s.w + b4.w;
        }
    } else {
        int c = (blockIdx.x - 12) * 64 + (t & 15) * 4;
        int kq = t >> 4;
        float4 aa = {0.f, 0.f, 0.f, 0.f}, ab = {0.f, 0.f, 0.f, 0.f};
#pragma unroll 8
        for (int i = 0; i < 48; ++i) {
            int k = kq * 48 + i;
            float4 w = *(const float4*)&Wk[(size_t)k * 768 + c];
            float g = ga[k], h = gb[k];
            aa.x = fmaf(g, w.x, aa.x); aa.y = fmaf(g, w.y, aa.y);
            aa.z = fmaf(g, w.z, aa.z); aa.w = fmaf(g, w.w, aa.w);
            ab.x = fmaf(h, w.x, ab.x); ab.y = fmaf(h, w.y, ab.y);
            ab.z = fmaf(h, w.z, ab.z); ab.w = fmaf(h, w.w, ab.w);
        }
        partA[kq][t & 15] = aa;
        partB[kq][t & 15] = ab;
        __syncthreads();
        if (t < 16) {
            float4 sa = {0.f, 0.f, 0.f, 0.f}, sb = {0.f, 0.f, 0.f, 0.f};
#pragma unroll
            for (int i = 0; i < 16; ++i) {
                float4 va = partA[i][t], vb = partB[i][t];
                sa.x += va.x; sa.y += va.y; sa.z += va.z; sa.w += va.w;
                sb.x += vb.x; sb.y += vb.y; sb.z += vb.z; sb.w += vb.w;
            }
            int cc = (blockIdx.x - 12) * 64 + t * 4;
            *(float4*)&colw[cc] = sa;
            *(float4*)&colw[768 + cc] = sb;
        }
    }
}

// ---------------------------------------------------------------------------
// prep_b: wkq[k][h] = (Wk[k,h48..] . q0_h)/sqrt(48); block 0 also computes
// Sgw[h] (at 12304) and CgbC[h] (at 12320) from colga/colgb + bk.
__global__ __launch_bounds__(256) void prep_b(
    const float* __restrict__ Wk, const float* __restrict__ bk,
    const float* __restrict__ q0, const float* __restrict__ colw,
    float* __restrict__ wkqc)
{
    __shared__ float qs[768];
    int t = threadIdx.x;
    qs[t] = q0[t]; qs[t + 256] = q0[t + 256]; qs[t + 512] = q0[t + 512];
    __syncthreads();
    const float invs = 0.14433756729740643f;  // 1/sqrt(48)
    int kl = t >> 4, h = t & 15;
    int k = blockIdx.x * 16 + kl;
    const float* wr = Wk + (size_t)k * 768 + h * 48;
    const float* qh = qs + h * 48;
    float a = 0.f;
#pragma unroll
    for (int d = 0; d < 48; d += 4) {
        float4 w = *(const float4*)&wr[d];
        a += w.x * qh[d] + w.y * qh[d + 1] + w.z * qh[d + 2] + w.w * qh[d + 3];
    }
    wkqc[k * 16 + h] = a * invs;
    if (blockIdx.x == 0 && t < 16) {
        float cd = 0.f, sa = 0.f, sb = 0.f;
        for (int d = 0; d < 48; ++d) {
            int dd = t * 48 + d;
            cd = fmaf(bk[dd], qs[dd], cd);
            sa = fmaf(colw[dd], qs[dd], sa);
            sb = fmaf(colw[768 + dd], qs[dd], sb);
        }
        wkqc[12304 + t] = sa * invs;
        wkqc[12320 + t] = sb * invs + cd * invs;
    }
}

// ---------------------------------------------------------------------------
// Pass 1: scores for all 8192 rows via raw moments + register-held wk.
// grid 1024 (8 rows/block). Per row: 2 barriers. Round-6 body verbatim
// (register-clean: no tail code, VGPR ~88, no wk spill).
__global__ __launch_bounds__(256) void ln_scores(
    const float* __restrict__ tf, const float* __restrict__ clsT,
    const float* __restrict__ ga, const float* __restrict__ wkqc,
    float* __restrict__ sc, float2* __restrict__ stats)
{
    __shared__ float tr[256][17];      // padded transpose buffer (17.4 KB)
    __shared__ float partw[4][16];
    __shared__ float red[2][4][2];     // s1,s2 per wave, row-parity dbuf
    int t = threadIdx.x;
    int l = t & 63, w = t >> 6;

    float wk0[16], wk1[16], wk2[16];
    {
        const float4* p0 = (const float4*)(wkqc + t * 16);
        const float4* p1 = (const float4*)(wkqc + (t + 256) * 16);
        const float4* p2 = (const float4*)(wkqc + (t + 512) * 16);
#pragma unroll
        for (int q = 0; q < 4; ++q) {
            float4 v0 = p0[q], v1 = p1[q], v2 = p2[q];
            wk0[q * 4] = v0.x; wk0[q * 4 + 1] = v0.y; wk0[q * 4 + 2] = v0.z; wk0[q * 4 + 3] = v0.w;
            wk1[q * 4] = v1.x; wk1[q * 4 + 1] = v1.y; wk1[q * 4 + 2] = v1.z; wk1[q * 4 + 3] = v1.w;
            wk2[q * 4] = v2.x; wk2[q * 4 + 1] = v2.y; wk2[q * 4 + 2] = v2.z; wk2[q * 4 + 3] = v2.w;
        }
    }
    float ga0 = ga[t], ga1 = ga[t + 256], ga2 = ga[t + 512];
    float Sg = wkqc[12304 + (t & 15)];
    float Cg = wkqc[12320 + (t & 15)];

    int r0 = blockIdx.x * 8;
    for (int r = 0; r < 8; ++r) {
        int row = r0 + r;
        int b = row >> 10, j = row & 1023;
        const float* src = j ? (tf + ((size_t)b * 1023 + (j - 1)) * 768) : clsT;
        float x0 = src[t], x1 = src[t + 256], x2 = src[t + 512];
        float s1 = x0 + x1 + x2;
        float s2 = fmaf(x0, x0, fmaf(x1, x1, x2 * x2));
        float g0 = ga0 * x0, g1 = ga1 * x1, g2 = ga2 * x2;
        float dt[16];
#pragma unroll
        for (int h = 0; h < 16; ++h)
            dt[h] = fmaf(g0, wk0[h], fmaf(g1, wk1[h], g2 * wk2[h]));
#pragma unroll
        for (int off = 1; off < 64; off <<= 1) {
            s1 += __shfl_xor(s1, off);
            s2 += __shfl_xor(s2, off);
        }
        if (l == 0) { red[r & 1][w][0] = s1; red[r & 1][w][1] = s2; }
#pragma unroll
        for (int h = 0; h < 16; ++h) tr[t][h] = dt[h];
        __syncthreads();                       // B1
        int hh = t & 15, ch = t >> 4;
        float v = 0.f;
#pragma unroll
        for (int i = 0; i < 16; ++i) v += tr[ch * 16 + i][hh];
        v += __shfl_xor(v, 16);
        v += __shfl_xor(v, 32);
        if (l < 16) partw[w][l] = v;
        __syncthreads();                       // B2
        if (t < 16) {
            float dtot = partw[0][t] + partw[1][t] + partw[2][t] + partw[3][t];
            float s1t = red[r & 1][0][0] + red[r & 1][1][0] + red[r & 1][2][0] + red[r & 1][3][0];
            float s2t = red[r & 1][0][1] + red[r & 1][1][1] + red[r & 1][2][1] + red[r & 1][3][1];
            float mean = s1t * (1.0f / 768.0f);
            float var = (s2t - mean * s1t) * (1.0f / 767.0f);
            float rden = 1.0f / (sqrtf(var) + 1e-6f);
            float sv = rden * (dtot - mean * Sg) + Cg;
            sc[(((size_t)b * 16 + t) << 10) + j] = sv;
            if (t == 0) stats[row] = make_float2(mean, rden);
        }
    }
}

// ---------------------------------------------------------------------------
// softmax over j (1024) per (b,h), emitting q = p*rden and c1 = sum q*mean.
// grid 128.
__global__ __launch_bounds__(256) void softmax_q(
    const float* __restrict__ sc, const float2* __restrict__ stats,
    float* __restrict__ qb, float* __restrict__ c1w)
{
    __shared__ float red[4];
    int bh = blockIdx.x, t = threadIdx.x;
    int b = bh >> 4;
    const float4* s4 = (const float4*)(sc + ((size_t)bh << 10));
    float4 v = s4[t];
    float m = fmaxf(fmaxf(v.x, v.y), fmaxf(v.z, v.w));
    float M = bmax256(m, red);
    float e0 = expf(v.x - M), e1 = expf(v.y - M), e2 = expf(v.z - M), e3 = expf(v.w - M);
    float Z = bsum256(e0 + e1 + e2 + e3, red);
    float2 st0 = stats[(b << 10) + 4 * t];
    float2 st1 = stats[(b << 10) + 4 * t + 1];
    float2 st2 = stats[(b << 10) + 4 * t + 2];
    float2 st3 = stats[(b << 10) + 4 * t + 3];
    float q0v = (e0 / Z) * st0.y, q1v = (e1 / Z) * st1.y;
    float q2v = (e2 / Z) * st2.y, q3v = (e3 / Z) * st3.y;
    float c1t = bsum256(q0v * st0.x + q1v * st1.x + q2v * st2.x + q3v * st3.x, red);
    float4 o4; o4.x = q0v; o4.y = q1v; o4.z = q2v; o4.w = q3v;
    ((float4*)(qb + ((size_t)bh << 10)))[t] = o4;
    if (t == 0) c1w[bh] = c1t;
}

// ---------------------------------------------------------------------------
// wsum partials: up[b][jc][h][:] = Σ_j qb*x over 32-row chunk. grid 256.
__global__ __launch_bounds__(256) void upart_k(
    const float* __restrict__ tf, const float* __restrict__ clsT,
    const float* __restrict__ qb, float* __restrict__ up)
{
    __shared__ float qs_s[16][32];
    int b = blockIdx.x & 7, jc = blockIdx.x >> 3;
    int t = threadIdx.x;
    if (t < 128) {
        int h = t >> 3, j4 = (t & 7) * 4;
        float4 pv = *(const float4*)(qb + (((size_t)b * 16 + h) << 10) + jc * 32 + j4);
        qs_s[h][j4] = pv.x; qs_s[h][j4 + 1] = pv.y;
        qs_s[h][j4 + 2] = pv.z; qs_s[h][j4 + 3] = pv.w;
    }
    __syncthreads();
    float acc[16][3];
#pragma unroll
    for (int h = 0; h < 16; ++h) { acc[h][0] = 0.f; acc[h][1] = 0.f; acc[h][2] = 0.f; }
    int j0 = jc * 32;
    const float* sp0 = j0 ? (tf + ((size_t)b * 1023 + (j0 - 1)) * 768) : clsT;
    float nx0 = sp0[t], nx1 = sp0[t + 256], nx2 = sp0[t + 512];
    for (int jj = 0; jj < 32; ++jj) {
        float x0 = nx0, x1 = nx1, x2 = nx2;
        if (jj < 31) {
            const float* sp = tf + ((size_t)b * 1023 + j0 + jj) * 768;
            nx0 = sp[t]; nx1 = sp[t + 256]; nx2 = sp[t + 512];
        }
#pragma unroll
        for (int h = 0; h < 16; ++h) {
            float qh = qs_s[h][jj];
            acc[h][0] = fmaf(qh, x0, acc[h][0]);
            acc[h][1] = fmaf(qh, x1, acc[h][1]);
            acc[h][2] = fmaf(qh, x2, acc[h][2]);
        }
    }
    float* o = up + (((size_t)b * 32 + jc) * 16) * 768;
#pragma unroll
    for (int h = 0; h < 16; ++h) {
        o[h * 768 + t] = acc[h][0];
        o[h * 768 + t + 256] = acc[h][1];
        o[h * 768 + t + 512] = acc[h][2];
    }
}

// ---------------------------------------------------------------------------
// o0 = (ga⊙(wsum−c1)+gb) @ Wv_h + bv. grid (16 h, 8 b).
__global__ __launch_bounds__(256) void o0_k(
    const float* __restrict__ up, const float* __restrict__ c1w,
    const float* __restrict__ ga, const float* __restrict__ gb,
    const float* __restrict__ Wv, const float* __restrict__ bv,
    float* __restrict__ o0)
{
    __shared__ float us[768];
    __shared__ float part[4][64];
    int h = blockIdx.x, b = blockIdx.y, t = threadIdx.x;
    float s0 = 0.f, s1 = 0.f, s2 = 0.f;
#pragma unroll 8
    for (int jc = 0; jc < 32; ++jc) {
        const float* q = up + (((size_t)b * 32 + jc) * 16 + h) * 768;
        s0 += q[t]; s1 += q[t + 256]; s2 += q[t + 512];
    }
    float c1 = c1w[b * 16 + h];
    us[t]       = ga[t] * (s0 - c1) + gb[t];
    us[t + 256] = ga[t + 256] * (s1 - c1) + gb[t + 256];
    us[t + 512] = ga[t + 512] * (s2 - c1) + gb[t + 512];
    __syncthreads();
    int dd = t & 63, kg = t >> 6;
    float a = 0.f;
    if (dd < 48) {
#pragma unroll 8
        for (int i = 0; i < 192; ++i) {
            int k = kg * 192 + i;
            a = fmaf(us[k], Wv[(size_t)k * 768 + h * 48 + dd], a);
        }
    }
    part[kg][dd] = a;
    __syncthreads();
    if (t < 48)
        o0[(size_t)b * 768 + h * 48 + t] =
            part[0][t] + part[1][t] + part[2][t] + part[3][t] + bv[h * 48 + t];
}

// ---------------------------------------------------------------------------
// x2 = clsT + o0 @ Wo + bo. grid (12, 8).
__global__ __launch_bounds__(256) void x2_k(
    const float* __restrict__ o0, const float* __restrict__ Wo,
    const float* __restrict__ bo, const float* __restrict__ clsT,
    float* __restrict__ x2w)
{
    __shared__ float ys[768];
    __shared__ float4 part[16][17];
    int b = blockIdx.y, t = threadIdx.x;
    const float* xr = o0 + (size_t)b * 768;
    ys[t] = xr[t]; ys[t + 256] = xr[t + 256]; ys[t + 512] = xr[t + 512];
    __syncthreads();
    int c = blockIdx.x * 64 + (t & 15) * 4;
    int kq = t >> 4;
    float4 acc = {0.f, 0.f, 0.f, 0.f};
#pragma unroll 8
    for (int i = 0; i < 48; ++i) {
        int k = kq * 48 + i;
        float4 w = *(const float4*)&Wo[(size_t)k * 768 + c];
        float y = ys[k];
        acc.x = fmaf(y, w.x, acc.x); acc.y = fmaf(y, w.y, acc.y);
        acc.z = fmaf(y, w.z, acc.z); acc.w = fmaf(y, w.w, acc.w);
    }
    part[kq][t & 15] = acc;
    __syncthreads();
    if (t < 16) {
        float4 s = {0.f, 0.f, 0.f, 0.f};
#pragma unroll
        for (int i = 0; i < 16; ++i) {
            float4 v = part[i][t];
            s.x += v.x; s.y += v.y; s.z += v.z; s.w += v.w;
        }
        int cc = blockIdx.x * 64 + t * 4;
        float4 b4 = *(const float4*)&bo[cc];
        float4 r4 = *(const float4*)&clsT[cc];
        float* o = x2w + (size_t)b * 768 + cc;
        o[0] = s.x + b4.x + r4.x; o[1] = s.y + b4.y + r4.y;
        o[2] = s.z + b4.z + r4.z; o[3] = s.w + b4.w + r4.w;
    }
}

// ---------------------------------------------------------------------------
// f1 = relu(LN2(x2) @ W1 + b1), LN fused. grid (24, 8).
__global__ __launch_bounds__(256) void f1_k(
    const float* __restrict__ x2w, const float* __restrict__ ga,
    const float* __restrict__ gb, const float* __restrict__ W1,
    const float* __restrict__ b1, float* __restrict__ f1w)
{
    __shared__ float ys[768];
    __shared__ float red[4];
    __shared__ float4 part[8][33];
    int b = blockIdx.y, t = threadIdx.x;
    const float* xr = x2w + (size_t)b * 768;
    float a0 = xr[t], a1 = xr[t + 256], a2 = xr[t + 512];
    float mean = bsum256(a0 + a1 + a2, red) * (1.0f / 768.0f);
    float d0 = a0 - mean, d1 = a1 - mean, d2 = a2 - mean;
    float var = bsum256(d0 * d0 + d1 * d1 + d2 * d2, red) * (1.0f / 767.0f);
    float den = sqrtf(var) + 1e-6f;
    ys[t]       = (ga[t] * d0) / den + gb[t];
    ys[t + 256] = (ga[t + 256] * d1) / den + gb[t + 256];
    ys[t + 512] = (ga[t + 512] * d2) / den + gb[t + 512];
    __syncthreads();
    int c = blockIdx.x * 128 + (t & 31) * 4;
    int kq = t >> 5;
    float4 acc = {0.f, 0.f, 0.f, 0.f};
#pragma unroll 8
    for (int i = 0; i < 96; ++i) {
        int k = kq * 96 + i;
        float4 w = *(const float4*)&W1[(size_t)k * 3072 + c];
        float y = ys[k];
        acc.x = fmaf(y, w.x, acc.x); acc.y = fmaf(y, w.y, acc.y);
        acc.z = fmaf(y, w.z, acc.z); acc.w = fmaf(y, w.w, acc.w);
    }
    part[kq][t & 31] = acc;
    __syncthreads();
    if (t < 32) {
        float4 s = {0.f, 0.f, 0.f, 0.f};
#pragma unroll
        for (int i = 0; i < 8; ++i) {
            float4 v = part[i][t];
            s.x += v.x; s.y += v.y; s.z += v.z; s.w += v.w;
        }
        int cc = blockIdx.x * 128 + t * 4;
        float4 b4 = *(const float4*)&b1[cc];
        float* o = f1w + (size_t)b * 3072 + cc;
        o[0] = fmaxf(s.x + b4.x, 0.f); o[1] = fmaxf(s.y + b4.y, 0.f);
        o[2] = fmaxf(s.z + b4.z, 0.f); o[3] = fmaxf(s.w + b4.w, 0.f);
    }
}

// ---------------------------------------------------------------------------
// x3 = x2 + f1 @ W2 + b2. grid (12, 8). Tail-free (round-6 form).
__global__ __launch_bounds__(256) void x3_k(
    const float* __restrict__ f1w, const float* __restrict__ W2,
    const float* __restrict__ b2, const float* __restrict__ x2w,
    float* __restrict__ x3w)
{
    __shared__ float ys[3072];
    __shared__ float4 part[16][17];
    int b = blockIdx.y, t = threadIdx.x;
    const float* xr = f1w + (size_t)b * 3072;
    for (int i = t; i < 3072; i += 256) ys[i] = xr[i];
    __syncthreads();
    int c = blockIdx.x * 64 + (t & 15) * 4;
    int kq = t >> 4;
    float4 acc = {0.f, 0.f, 0.f, 0.f};
#pragma unroll 8
    for (int i = 0; i < 192; ++i) {
        int k = kq * 192 + i;
        float4 w = *(const float4*)&W2[(size_t)k * 768 + c];
        float y = ys[k];
        acc.x = fmaf(y, w.x, acc.x); acc.y = fmaf(y, w.y, acc.y);
        acc.z = fmaf(y, w.z, acc.z); acc.w = fmaf(y, w.w, acc.w);
    }
    part[kq][t & 15] = acc;
    __syncthreads();
    if (t < 16) {
        float4 s = {0.f, 0.f, 0.f, 0.f};
#pragma unroll
        for (int i = 0; i < 16; ++i) {
            float4 v = part[i][t];
            s.x += v.x; s.y += v.y; s.z += v.z; s.w += v.w;
        }
        int cc = blockIdx.x * 64 + t * 4;
        float4 b4 = *(const float4*)&b2[cc];
        const float* x2r = x2w + (size_t)b * 768 + cc;
        float* o = x3w + (size_t)b * 768 + cc;
        o[0] = x2r[0] + s.x + b4.x; o[1] = x2r[1] + s.y + b4.y;
        o[2] = x2r[2] + s.z + b4.z; o[3] = x2r[3] + s.w + b4.w;
    }
}

// ---------------------------------------------------------------------------
// Head logits, k-split: block (kg, b) computes double partials over k-chunk
// kg*96..+96 for 100 pool cols + 7 class cols. LNf fused. lp[b][kg][112].
__global__ __launch_bounds__(256) void logits_part(
    const float* __restrict__ x3w, const float* __restrict__ ga,
    const float* __restrict__ gb, const float* __restrict__ Wpool,
    const float* __restrict__ Wcls, double* __restrict__ lp)
{
    __shared__ float ys[768];
    __shared__ float red[4];
    int kg = blockIdx.x, b = blockIdx.y, t = threadIdx.x;
    const float* xr = x3w + (size_t)b * 768;
    float a0 = xr[t], a1 = xr[t + 256], a2 = xr[t + 512];
    float mean = bsum256(a0 + a1 + a2, red) * (1.0f / 768.0f);
    float d0 = a0 - mean, d1 = a1 - mean, d2 = a2 - mean;
    float var = bsum256(d0 * d0 + d1 * d1 + d2 * d2, red) * (1.0f / 767.0f);
    float den = sqrtf(var) + 1e-6f;
    ys[t]       = (ga[t] * d0) / den + gb[t];
    ys[t + 256] = (ga[t + 256] * d1) / den + gb[t + 256];
    ys[t + 512] = (ga[t + 512] * d2) / den + gb[t + 512];
    __syncthreads();
    int kbase = kg * 96;
    if (t < 100) {
        double a = 0.0;
#pragma unroll 8
        for (int i = 0; i < 96; ++i) {
            int k = kbase + i;
            a = fma((double)ys[k], (double)Wpool[k * 100 + t], a);
        }
        lp[((size_t)b * 8 + kg) * 112 + t] = a;
    } else if (t < 107) {
        int c = t - 100;
        double a = 0.0;
#pragma unroll 8
        for (int i = 0; i < 96; ++i) {
            int k = kbase + i;
            a = fma((double)ys[k], (double)Wcls[k * 7 + c], a);
        }
        lp[((size_t)b * 8 + kg) * 112 + t] = a;
    }
}

// ---------------------------------------------------------------------------
// Head decide: sum 8 partials (fixed order), pool softmax, class logits out,
// entropy -> adjusted_k, stable descending rank. grid 8, block 128, double.
__global__ __launch_bounds__(128) void head_decide(
    const double* __restrict__ lp, const float* __restrict__ bpool,
    const float* __restrict__ bcls, float* __restrict__ out,
    int* __restrict__ topw, int* __restrict__ kkw)
{
    __shared__ double sP[100];
    __shared__ double sC7[7];
    int b = blockIdx.x, t = threadIdx.x;
    if (t < 107) {
        double a = (t < 100) ? (double)bpool[t] : (double)bcls[t - 100];
#pragma unroll
        for (int kg = 0; kg < 8; ++kg) a += lp[((size_t)b * 8 + kg) * 112 + t];
        if (t < 100) sP[t] = a;
        else {
            sC7[t - 100] = a;
            out[OUT_CLS_OFF + b * 7 + (t - 100)] = (float)a;
        }
    }
    __syncthreads();
    double mx = sP[0];
    for (int j = 1; j < 100; ++j) mx = fmax(mx, sP[j]);
    double e = (t < 100) ? exp(sP[t] - mx) : 0.0;
    __syncthreads();
    if (t < 100) sP[t] = e;
    __syncthreads();
    double zs = 0.0;
    for (int j = 0; j < 100; ++j) zs += sP[j];
    __syncthreads();
    if (t < 100) sP[t] = e / zs;
    __syncthreads();
    if (t == 0) {
        double m7 = sC7[0];
        for (int j = 1; j < 7; ++j) m7 = fmax(m7, sC7[j]);
        double es[7]; double z = 0.0;
        for (int j = 0; j < 7; ++j) { es[j] = exp(sC7[j] - m7); z += es[j]; }
        double ent = 0.0;
        for (int j = 0; j < 7; ++j) { double pr = es[j] / z; ent -= pr * log(pr + 1e-9); }
        double ne = ent / log(7.0);
        int kk = (int)floor(1.0 + ne * 99.0);
        kkw[b] = kk < 1 ? 1 : (kk > 100 ? 100 : kk);
    }
    if (t < 100) {
        double pi = sP[t];
        int r = 0;
        for (int j = 0; j < 100; ++j) {
            double pj = sP[j];
            r += (pj > pi) || (pj == pi && j < t);
        }
        topw[b * 100 + r] = t;   // descending, stable (lower index first)
    }
}

// ---------------------------------------------------------------------------
// gather: out[b, r, :] = (r < kk[b]) ? pool[top[b][r], :] : 0. grid (100, 8).
__global__ __launch_bounds__(192) void gather_k(
    const float* __restrict__ pool, const int* __restrict__ topw,
    const int* __restrict__ kkw, float* __restrict__ out)
{
    int r = blockIdx.x, b = blockIdx.y, t = threadIdx.x;
    int idx = topw[b * 100 + r];
    bool keep = r < kkw[b];
    const float4* src = (const float4*)(pool + (size_t)idx * 768);
    float4* dst = (float4*)(out + (size_t)b * 76800 + (size_t)r * 768);
    float4 z = {0.f, 0.f, 0.f, 0.f};
    dst[t] = keep ? src[t] : z;
}

// ---------------------------------------------------------------------------
extern "C" void kernel_launch(void* const* d_in, const int* in_sizes, int n_in,
                              void* d_out, int out_size, void* d_ws, size_t ws_size,
                              hipStream_t stream) {
    (void)in_sizes; (void)n_in; (void)out_size; (void)ws_size;
    const float* tf    = (const float*)d_in[0];
    const float* pool  = (const float*)d_in[1];
    const float* clsT  = (const float*)d_in[2];
    const float* Wq    = (const float*)d_in[3];
    const float* bq    = (const float*)d_in[4];
    const float* Wk    = (const float*)d_in[5];
    const float* bk    = (const float*)d_in[6];
    const float* Wv    = (const float*)d_in[7];
    const float* bv    = (const float*)d_in[8];
    const float* Wo    = (const float*)d_in[9];
    const float* bo    = (const float*)d_in[10];
    const float* ln1a  = (const float*)d_in[11];
    const float* ln1b  = (const float*)d_in[12];
    const float* ln2a  = (const float*)d_in[13];
    const float* ln2b  = (const float*)d_in[14];
    const float* W1    = (const float*)d_in[15];
    const float* b1    = (const float*)d_in[16];
    const float* W2    = (const float*)d_in[17];
    const float* b2    = (const float*)d_in[18];
    const float* lnfa  = (const float*)d_in[19];
    const float* lnfb  = (const float*)d_in[20];
    const float* Wpool = (const float*)d_in[21];
    const float* bpool = (const float*)d_in[22];
    const float* Wcls  = (const float*)d_in[23];
    const float* bcls  = (const float*)d_in[24];
    float* out = (float*)d_out;
    char* ws = (char*)d_ws;

    float*  sc    = (float*)(ws + 0);           // 524,288
    float*  qb    = (float*)(ws + 524288);      // 524,288
    float2* stats = (float2*)(ws + 1048576);    // 65,536
    float*  wkqc  = (float*)(ws + 1114112);     // 49,408
    float*  q0    = (float*)(ws + 1163520);     // 3,072
    float*  colw  = (float*)(ws + 1166592);     // 6,144
    float*  c1w   = (float*)(ws + 1172736);     // 512
    float*  up    = (float*)(ws + 1173248);     // 12,582,912
    float*  o0    = (float*)(ws + 13756160);    // 24,576
    float*  x2w   = (float*)(ws + 13780736);    // 24,576
    float*  f1w   = (float*)(ws + 13805312);    // 98,304
    float*  x3w   = (float*)(ws + 13903616);    // 24,576
    int*    topw  = (int*)(ws + 13928192);      // 3,200
    int*    kkw   = (int*)(ws + 13931392);      // 32
    double* lp    = (double*)(ws + 13931424);   // 57,344  (total ~14 MB)

    prep_a<<<24, 256, 0, stream>>>(clsT, ln1a, ln1b, Wq, bq, Wk, q0, colw);
    prep_b<<<48, 256, 0, stream>>>(Wk, bk, q0, colw, wkqc);
    ln_scores<<<1024, 256, 0, stream>>>(tf, clsT, ln1a, wkqc, sc, stats);
    softmax_q<<<128, 256, 0, stream>>>(sc, stats, qb, c1w);
    upart_k<<<256, 256, 0, stream>>>(tf, clsT, qb, up);
    o0_k<<<dim3(16, 8), 256, 0, stream>>>(up, c1w, ln1a, ln1b, Wv, bv, o0);
    x2_k<<<dim3(12, 8), 256, 0, stream>>>(o0, Wo, bo, clsT, x2w);
    f1_k<<<dim3(24, 8), 256, 0, stream>>>(x2w, ln2a, ln2b, W1, b1, f1w);
    x3_k<<<dim3(12, 8), 256, 0, stream>>>(f1w, W2, b2, x2w, x3w);
    logits_part<<<dim3(8, 8), 256, 0, stream>>>(x3w, lnfa, lnfb, Wpool, Wcls, lp);
    head_decide<<<8, 128, 0, stream>>>(lp, bpool, bcls, out, topw, kkw);
    gather_k<<<dim3(100, 8), 192, 0, stream>>>(pool, topw, kkw, out);
}